// Round 12
// baseline (259.634 us; speedup 1.0000x reference)
//
#include <hip/hip_runtime.h>
#include <math.h>

// ASFF_2: N=8, C1=256, C2=512, H=64, W=64, low-res 32x32.
// CARAFE-commutation rewrite: u = w_up@CARAFE(in2)+b_up == CARAFE(z)+b_up with
// z = w_up@in2 (low-res GEMM, 4x fewer FLOPs); v2 = w_l2@u == CARAFE(zw)+c2 with
// zw = (w_l2@w_up)@in2, c2 = w_l2@b_up. Exact (masks sum to 1; bias kept outside
// so zero-padded border taps match the reference).
//  K1 down_gemm: ktT = bf16T(w_down @ input2 + b_down)  [N,34*34,128] padded
//  K2 enc_mfma -> kt2 ; K3 softmax -> maskb
//  in2t: input2 -> in2T bf16 [n][1024][512]
//  zgemm: zbfT = bf16(w_up @ in2T) [n][1024][256]   (m97+T4 structure)
//  zw: zwT = ww2 @ input2 [n][1024][8] fp32
//  carafe_fuse: u=CARAFE(z)+b_up, lw0 softmax, blend -> fusedT bf16 [66x66][256]
//  K7 m97+T4 9-tap conv GEMM + BN + SiLU -> out

#define EPS 1e-5f
typedef unsigned short u16;
typedef __attribute__((ext_vector_type(8))) __bf16 bf16x8;
typedef __attribute__((ext_vector_type(4))) float f32x4;

#define VMCNT(N) asm volatile("s_waitcnt vmcnt(" #N ")" ::: "memory")

__device__ inline u16 f2bf(float x) {
    union { float f; unsigned u; } v; v.f = x;
    unsigned r = v.u + 0x7FFF + ((v.u >> 16) & 1);
    return (u16)(r >> 16);
}
__device__ inline float bf2f(u16 x) {
    union { unsigned u; float f; } v; v.u = (unsigned)x << 16; return v.f;
}

// ---------------- K1: fp32 tiled GEMM, bf16-transposed-padded output ----------------
__global__ __launch_bounds__(256) void down_gemm_kernel(
    const float* __restrict__ A, const float* __restrict__ B,
    const float* __restrict__ bias, u16* __restrict__ ktT)
{
    const int n = blockIdx.z;
    const float* Bn = B + (long)n * 512 * 1024;
    __shared__ __align__(16) float As[16][68];
    __shared__ __align__(16) float Bs[16][64];
    const int tid = threadIdx.x;
    const int tcol = tid & 15;
    const int trow = tid >> 4;
    const int rowBase = blockIdx.y * 64;
    const int colBase = blockIdx.x * 64;
    float acc[4][4] = {};
    for (int k0 = 0; k0 < 512; k0 += 16) {
#pragma unroll
        for (int i = 0; i < 4; ++i) {
            int idx = i * 256 + tid;
            int r = idx >> 4, cc = idx & 15;
            As[cc][r] = A[(long)(rowBase + r) * 512 + k0 + cc];
        }
#pragma unroll
        for (int i = 0; i < 4; ++i) {
            int idx = i * 256 + tid;
            int r = idx >> 6, cc = idx & 63;
            Bs[r][cc] = Bn[(long)(k0 + r) * 1024 + colBase + cc];
        }
        __syncthreads();
#pragma unroll
        for (int kk = 0; kk < 16; ++kk) {
            float4 a4 = *reinterpret_cast<const float4*>(&As[kk][trow * 4]);
            float4 b4 = *reinterpret_cast<const float4*>(&Bs[kk][tcol * 4]);
            float a[4] = {a4.x, a4.y, a4.z, a4.w};
            float b[4] = {b4.x, b4.y, b4.z, b4.w};
#pragma unroll
            for (int i = 0; i < 4; ++i)
#pragma unroll
                for (int j = 0; j < 4; ++j)
                    acc[i][j] += a[i] * b[j];
        }
        __syncthreads();
    }
    u16* Kn = ktT + (long)n * 1156 * 128;
#pragma unroll
    for (int i = 0; i < 4; ++i) {
        int ch = rowBase + trow * 4 + i;
        float bv = bias[ch];
#pragma unroll
        for (int j = 0; j < 4; ++j) {
            int p = colBase + tcol * 4 + j;
            int pr = ((p >> 5) + 1) * 34 + (p & 31) + 1;
            Kn[pr * 128 + ch] = f2bf(acc[i][j] + bv);
        }
    }
}

// ---------------- K2: encoder conv as 9-tap shifted MFMA GEMM ----------------
__global__ __launch_bounds__(64) void enc_mfma_kernel(
    const u16* __restrict__ A, const u16* __restrict__ B,
    const float* __restrict__ bias, float* __restrict__ C)
{
    const int n = blockIdx.y;
    const int lane = threadIdx.x;
    const int lr = lane & 15, lk = lane >> 4;
    const int p = blockIdx.x * 16 + lr;
    const int pr = ((p >> 5) + 1) * 34 + (p & 31) + 1;
    const u16* Bn = B + (long)n * 1156 * 128;
    const int bOff = pr * 128 + lk * 8;
    f32x4 acc[3] = {};
    for (int t = 0; t < 9; ++t) {
        const u16* At = A + t * 8192;
        const int btap = ((t / 3 - 1) * 34 + (t % 3 - 1)) * 128;
#pragma unroll
        for (int k0 = 0; k0 < 128; k0 += 32) {
            bf16x8 bf = *(const bf16x8*)(Bn + bOff + btap + k0);
#pragma unroll
            for (int mf = 0; mf < 3; ++mf) {
                bf16x8 af = *(const bf16x8*)(At + (mf * 16 + lr) * 128 + lk * 8 + k0);
                acc[mf] = __builtin_amdgcn_mfma_f32_16x16x32_bf16(af, bf, acc[mf], 0, 0, 0);
            }
        }
    }
    float* Cn = C + (long)n * 36 * 1024;
#pragma unroll
    for (int mf = 0; mf < 3; ++mf)
#pragma unroll
        for (int reg = 0; reg < 4; ++reg) {
            int co = mf * 16 + lk * 4 + reg;
            if (co < 36)
                Cn[(long)co * 1024 + p] = acc[mf][reg] + bias[co];
        }
}

// ---------------- K3: softmax over k=9 ----------------
__global__ __launch_bounds__(256) void mask_softmax_kernel(
    const float* __restrict__ kt2, float* __restrict__ mask)
{
    int gid = blockIdx.x * 256 + threadIdx.x;   // N*1024*4
    int q = gid & 3;
    int p = (gid >> 2) & 1023;
    int n = gid >> 12;
    float s[9];
    float mx = -1e30f;
#pragma unroll
    for (int k = 0; k < 9; ++k) {
        s[k] = kt2[(long)(n * 36 + k * 4 + q) * 1024 + p];
        mx = fmaxf(mx, s[k]);
    }
    float sum = 0.f;
#pragma unroll
    for (int k = 0; k < 9; ++k) { s[k] = expf(s[k] - mx); sum += s[k]; }
    float inv = 1.f / sum;
    float* mp = mask + (long)(n * 1024 + p) * 36 + q;
#pragma unroll
    for (int k = 0; k < 9; ++k) mp[k * 4] = s[k] * inv;
}

// ---------------- in2t: transpose-cast input2 [512][1024] -> in2T bf16 [q][512] ----------------
__global__ __launch_bounds__(256) void in2t_kernel(
    const float* __restrict__ src0, u16* __restrict__ dst)
{
    __shared__ u16 lds[32 * 514];
    const int n = blockIdx.y;
    const int p0 = blockIdx.x * 32;
    const int tid = threadIdx.x;
    {
        const int w = tid & 31;
        const int chunk = tid >> 5;
        const float* src = src0 + (long)n * 512 * 1024 + p0 + w;
        for (int ci = chunk * 64; ci < chunk * 64 + 64; ++ci)
            lds[w * 514 + ci] = f2bf(src[(long)ci * 1024]);
    }
    __syncthreads();
    const int px = tid >> 3;
    const int qd = tid & 7;
    u16* drow = dst + ((long)n * 1024 + p0 + px) * 512;
    const u16* lrow = lds + px * 514;
#pragma unroll
    for (int j = 0; j < 32; ++j) {
        int off = j * 16 + qd * 2;
        *(unsigned*)(drow + off) = *(const unsigned*)(lrow + off);
    }
}

// ---------------- staging macros (shared by zgemm / gemm_m97) ----------------
#define STAGE_A(dstp, t, kx)                                                         \
    {                                                                                \
        const u16* Abase = A + ((long)(t) * 256 + rowBase) * KCC + (kx) * 32;        \
        _Pragma("unroll")                                                            \
        for (int ii = 0; ii < 2; ++ii) {                                             \
            int f = ii * 256 + tid;                                                  \
            int r = f >> 2, uu = f & 3;                                              \
            __builtin_amdgcn_global_load_lds(                                        \
                (const __attribute__((address_space(1))) void*)                      \
                    (Abase + (long)r * KCC + ((uu ^ ((r >> 1) & 3)) << 3)),          \
                (__attribute__((address_space(3))) void*)((dstp) + f * 8),           \
                16, 0, 0);                                                           \
        }                                                                            \
    }

#define STAGE_B(dstp, kx)                                                            \
    {                                                                                \
        const u16* Bbase = Bn + (long)g0 * KCC + (kx) * 32;                          \
        for (int f = tid; f < BUNITS; f += 256) {                                    \
            int r = f >> 2, uu = f & 3;                                              \
            __builtin_amdgcn_global_load_lds(                                        \
                (const __attribute__((address_space(1))) void*)                      \
                    (Bbase + (long)r * KCC + ((uu ^ ((r >> 1) & 3)) << 3)),          \
                (__attribute__((address_space(3))) void*)((dstp) + f * 8),           \
                16, 0, 0);                                                           \
        }                                                                            \
    }

// ---------------- zgemm: zbfT = bf16(w_up @ in2T)  [n][1024][256] ----------------
// m97+T4 structure (KCC=512, no taps, no bias); transposed bf16 epilogue.
__global__ __launch_bounds__(256, 2) void zgemm_kernel(
    const u16* __restrict__ A,      // wupT [256][512]
    const u16* __restrict__ B,      // in2T [n][1024][512]
    u16* __restrict__ Z)            // zbfT [n][1024][256]
{
    constexpr int KCC = 512;
    constexpr int BUNITS = 512;
    constexpr int NKX = 16;
    __shared__ __align__(16) u16 lsA[3][128 * 32];
    __shared__ __align__(16) u16 lsB[3][128 * 32];
    const int n = blockIdx.z;
    const u16* Bn = B + (long)n * 1024 * 512;
    const int tid = threadIdx.x;
    const int lane = tid & 63;
    const int wid = tid >> 6;
    const int mw = wid >> 1, nw = wid & 1;
    const int lr = lane & 15, lk = lane >> 4;
    const int rowBase = blockIdx.y * 128;
    const int colBase = blockIdx.x * 128;
    const int g0 = colBase;

    STAGE_B(lsB[0], 0);
    STAGE_A(lsA[0], 0, 0);

    const int aswz = (lk ^ ((lr >> 1) & 3)) << 3;
    int aoff[4];
#pragma unroll
    for (int mf = 0; mf < 4; ++mf)
        aoff[mf] = (mw * 64 + mf * 16 + lr) * 32 + aswz;

    f32x4 acc[4][4] = {};
    for (int kx = 0; kx < NKX; ++kx) {
        const bool lastS = (kx == NKX - 1);
        if (!lastS) {
            STAGE_B(lsB[(kx + 1) % 3], kx + 1);
            STAGE_A(lsA[(kx + 1) % 3], 0, kx + 1);
        }
        if (lastS) { VMCNT(0); } else { VMCNT(4); }
        __builtin_amdgcn_s_barrier();
        asm volatile("" ::: "memory");
        const u16* la = lsA[kx % 3];
        const u16* lb = lsB[kx % 3];
        bf16x8 af[4], bfr[4];
#pragma unroll
        for (int mf = 0; mf < 4; ++mf)
            af[mf] = *(const bf16x8*)(la + aoff[mf]);
        const int rb = nw * 64 + lr;
        const int bswz = (lk ^ ((rb >> 1) & 3)) << 3;
#pragma unroll
        for (int nf = 0; nf < 4; ++nf)
            bfr[nf] = *(const bf16x8*)(lb + (rb + nf * 16) * 32 + bswz);
#pragma unroll
        for (int mf = 0; mf < 4; ++mf)
#pragma unroll
            for (int nf = 0; nf < 4; ++nf)
                acc[mf][nf] = __builtin_amdgcn_mfma_f32_16x16x32_bf16(
                    af[mf], bfr[nf], acc[mf][nf], 0, 0, 0);
    }

    u16* Zn = Z + (long)n * 1024 * 256;
#pragma unroll
    for (int mf = 0; mf < 4; ++mf) {
        const int co0 = rowBase + mw * 64 + mf * 16 + lk * 4;
#pragma unroll
        for (int nf = 0; nf < 4; ++nf) {
            const int col = colBase + nw * 64 + nf * 16 + lr;
            unsigned lo = (unsigned)f2bf(acc[mf][nf][0]) |
                          ((unsigned)f2bf(acc[mf][nf][1]) << 16);
            unsigned hi = (unsigned)f2bf(acc[mf][nf][2]) |
                          ((unsigned)f2bf(acc[mf][nf][3]) << 16);
            *(uint2*)(Zn + (long)col * 256 + co0) = make_uint2(lo, hi);
        }
    }
}

// ---------------- zw: zwT = ww2 @ input2  [n][1024][8] fp32 ----------------
__global__ __launch_bounds__(256) void zw_kernel(
    const float* __restrict__ in2, const float* __restrict__ ww2,
    float* __restrict__ zwT)
{
    const int n = blockIdx.y;
    const int q = blockIdx.x * 256 + threadIdx.x;
    const float* ip = in2 + (long)n * 512 * 1024 + q;
    float s[8] = {};
    for (int ci = 0; ci < 512; ++ci) {
        float x = ip[(long)ci * 1024];
#pragma unroll
        for (int j = 0; j < 8; ++j) s[j] += ww2[j * 512 + ci] * x;
    }
    float* o = zwT + ((long)n * 1024 + q) * 8;
    *(float4*)o = make_float4(s[0], s[1], s[2], s[3]);
    *(float4*)(o + 4) = make_float4(s[4], s[5], s[6], s[7]);
}

// ---------------- border_zero: zero the 66x66 pad ring of fusedT ----------------
__global__ __launch_bounds__(256) void border_zero_kernel(u16* __restrict__ ftb)
{
    int gid = blockIdx.x * 256 + threadIdx.x;   // 8 * 260 * 32 uint4
    if (gid >= 8 * 260 * 32) return;
    int n = gid / (260 * 32);
    int rem = gid - n * (260 * 32);
    int r = rem >> 5;
    int i = rem & 31;
    int h, w;
    if (r < 66)       { h = 0;  w = r; }
    else if (r < 132) { h = 65; w = r - 66; }
    else { int j = r - 132; h = 1 + (j >> 1); w = (j & 1) * 65; }
    long prow = (long)h * 66 + w;
    uint4* dst = (uint4*)(ftb + (long)n * 4356 * 256 + prow * 256) + i;
    *dst = make_uint4(0, 0, 0, 0);
}

// ---------------- carafe_fuse: u=CARAFE(z)+b_up, lw0, blend -> fusedT ----------------
// Block: one image row h, 32 px. LDS z-tile 3x18 lowres px x 256ch bf16.
__global__ __launch_bounds__(256) void carafe_fuse_kernel(
    const float* __restrict__ i1g, const u16* __restrict__ zbfT,
    const float* __restrict__ zwT, const float* __restrict__ maskb,
    const float* __restrict__ bnp,          // 512..519 c2, 768.. b_up
    const float* __restrict__ w_l1, const float* __restrict__ bn_l1,
    const float* __restrict__ bn_l2, const float* __restrict__ w_wl,
    const float* __restrict__ b_wl, u16* __restrict__ dst)
{
    __shared__ float red[8][32][8];         // 8 KB
    __shared__ float lw0s[32];
    __shared__ u16 zbf[54 * 260];           // 28.1 KB
    __shared__ float zwl[54 * 8];           // 1.7 KB
    __shared__ float mlds[16 * 36];         // 2.3 KB
    __shared__ u16 lds2[32 * 260];          // 16.6 KB
    const int n = blockIdx.y;
    const int h = blockIdx.x >> 1;
    const int w0 = (blockIdx.x & 1) << 5;
    const int hq = h >> 1;
    const int wq0 = w0 >> 1;
    const int tid = threadIdx.x;

    for (int idx = tid; idx < 54 * 64; idx += 256) {
        int px = idx >> 6, quad = idx & 63;
        int r = px / 18, c = px - r * 18;
        int gr = hq - 1 + r, gc = wq0 - 1 + c;
        uint2 v = make_uint2(0u, 0u);
        if (gr >= 0 && gr < 32 && gc >= 0 && gc < 32)
            v = *(const uint2*)(zbfT + ((long)n * 1024 + gr * 32 + gc) * 256 + quad * 4);
        *(uint2*)(zbf + px * 260 + quad * 4) = v;
    }
    for (int idx = tid; idx < 108; idx += 256) {
        int px = idx >> 1, half = idx & 1;
        int r = px / 18, c = px - r * 18;
        int gr = hq - 1 + r, gc = wq0 - 1 + c;
        float4 v = make_float4(0.f, 0.f, 0.f, 0.f);
        if (gr >= 0 && gr < 32 && gc >= 0 && gc < 32)
            v = *(const float4*)(zwT + ((long)n * 1024 + gr * 32 + gc) * 8 + half * 4);
        *(float4*)(zwl + px * 8 + half * 4) = v;
    }
    for (int idx = tid; idx < 576; idx += 256)
        mlds[idx] = maskb[((long)n * 1024 + hq * 32 + wq0) * 36 + idx];
    __syncthreads();

    const int w = tid & 31;
    const int chunk = tid >> 5;
    const int p = (h << 6) + w0 + w;
    const float* i1 = i1g + ((long)n * 256 * 4096) + p;
    {   // pass1: v1 partials
        float s1[8] = {};
        for (int ci = chunk * 32; ci < chunk * 32 + 32; ++ci) {
            float x1 = i1[(long)ci * 4096];
#pragma unroll
            for (int j = 0; j < 8; ++j) s1[j] += w_l1[j * 256 + ci] * x1;
        }
#pragma unroll
        for (int j = 0; j < 8; ++j) red[chunk][w][j] = s1[j];
    }
    __syncthreads();
    {   // reduce: 32 px x 8 j = 256 cells
        int px = tid >> 3, j = tid & 7;
        float s = 0.f;
#pragma unroll
        for (int o = 0; o < 8; ++o) s += red[o][px][j];
        red[0][px][j] = s;
    }
    __syncthreads();
    if (tid < 32) {
        const int wp = w0 + tid;
        const int wqm = (wp >> 1) - wq0;        // 0..15
        const int q = ((h & 1) << 1) | (wp & 1);
        float m9[9];
#pragma unroll
        for (int k = 0; k < 9; ++k) m9[k] = mlds[wqm * 36 + k * 4 + q];
        float v[16];
#pragma unroll
        for (int j = 0; j < 8; ++j) v[j] = red[0][tid][j];
#pragma unroll
        for (int j = 0; j < 8; ++j) v[8 + j] = bnp[512 + j];   // c2
#pragma unroll
        for (int k = 0; k < 9; ++k) {
            int dh = k / 3 - 1, dw = k - (k / 3) * 3 - 1;
            const float* zp = zwl + ((1 + dh) * 18 + wqm + 1 + dw) * 8;
            float mk = m9[k];
#pragma unroll
            for (int j = 0; j < 8; ++j) v[8 + j] += mk * zp[j];
        }
        float z0 = b_wl[0], z1 = b_wl[1];
#pragma unroll
        for (int j = 0; j < 8; ++j) {
            float g = bn_l1[j], b = bn_l1[8 + j], m = bn_l1[16 + j], va = bn_l1[24 + j];
            float y = (v[j] - m) * (g * rsqrtf(va + EPS)) + b;
            float sv = y / (1.f + expf(-y));
            z0 += w_wl[j] * sv;
            z1 += w_wl[16 + j] * sv;
            g = bn_l2[j]; b = bn_l2[8 + j]; m = bn_l2[16 + j]; va = bn_l2[24 + j];
            y = (v[8 + j] - m) * (g * rsqrtf(va + EPS)) + b;
            sv = y / (1.f + expf(-y));
            z0 += w_wl[8 + j] * sv;
            z1 += w_wl[24 + j] * sv;
        }
        lw0s[tid] = 1.f / (1.f + expf(z1 - z0));
    }
    __syncthreads();
    {   // pass2: u = CARAFE(z)+b_up ; blend ; bf16 into lds2
        const float lw = lw0s[w], lw1 = 1.f - lw;
        const int wp = w0 + w;
        const int wqm = (wp >> 1) - wq0;
        const int q = ((h & 1) << 1) | (wp & 1);
        float m9[9];
#pragma unroll
        for (int k = 0; k < 9; ++k) m9[k] = mlds[wqm * 36 + k * 4 + q];
        for (int ci = chunk * 32; ci < chunk * 32 + 32; ci += 4) {
            float4 b4 = *(const float4*)(bnp + 768 + ci);
            float uu[4] = {b4.x, b4.y, b4.z, b4.w};
#pragma unroll
            for (int k = 0; k < 9; ++k) {
                int dh = k / 3 - 1, dw = k - (k / 3) * 3 - 1;
                uint2 vz = *(const uint2*)(zbf + ((1 + dh) * 18 + wqm + 1 + dw) * 260 + ci);
                float mk = m9[k];
                uu[0] += mk * bf2f((u16)(vz.x & 0xffff));
                uu[1] += mk * bf2f((u16)(vz.x >> 16));
                uu[2] += mk * bf2f((u16)(vz.y & 0xffff));
                uu[3] += mk * bf2f((u16)(vz.y >> 16));
            }
            unsigned o01 = (unsigned)f2bf(i1[(long)ci * 4096] * lw + uu[0] * lw1)
                         | ((unsigned)f2bf(i1[(long)(ci + 1) * 4096] * lw + uu[1] * lw1) << 16);
            unsigned o23 = (unsigned)f2bf(i1[(long)(ci + 2) * 4096] * lw + uu[2] * lw1)
                         | ((unsigned)f2bf(i1[(long)(ci + 3) * 4096] * lw + uu[3] * lw1) << 16);
            *(uint2*)(lds2 + w * 260 + ci) = make_uint2(o01, o23);
        }
    }
    __syncthreads();
    {   // transposed padded write
        const int px = tid >> 3, qd = tid & 7;
        const int pg = (h << 6) + w0 + px;
        long prow = (long)((pg >> 6) + 1) * 66 + (pg & 63) + 1;
        u16* drow = dst + (long)n * 4356 * 256 + prow * 256;
        const u16* lrow = lds2 + px * 260;
#pragma unroll
        for (int j = 0; j < 16; ++j) {
            int off = j * 16 + qd * 2;
            *(unsigned*)(drow + off) = *(const unsigned*)(lrow + off);
        }
    }
}

// ---------------- K7: m97+T4 GEMM — triple-buf LDS, counted vmcnt ----------------
template<int KCC, int NT, bool PADDED>
__global__ __launch_bounds__(256, 2) void gemm_m97_kernel(
    const u16* __restrict__ A,      // [NT][256][KCC] bf16
    const u16* __restrict__ B,      // per image [rows][KCC] bf16
    const float* __restrict__ scale, const float* __restrict__ shift,
    float* __restrict__ C, long strideB, long strideC, int silu)
{
    constexpr int RROWS = PADDED ? 264 : 128;
    constexpr int BUNITS = RROWS * 4;
    constexpr int NKX = KCC / 32;
    constexpr int MINB = BUNITS / 256;
    __shared__ __align__(16) u16 lsA[3][128 * 32];
    __shared__ __align__(16) u16 lsB[3][RROWS * 32];
    const int n = blockIdx.z;
    const u16* Bn = B + (long)n * strideB;
    float* Cn = C + (long)n * strideC;
    const int tid = threadIdx.x;
    const int lane = tid & 63;
    const int wid = tid >> 6;
    const int mw = wid >> 1, nw = wid & 1;
    const int lr = lane & 15, lk = lane >> 4;
    const int rowBase = blockIdx.y * 128;
    const int colBase = blockIdx.x * 128;
    const int g0 = PADDED ? (colBase >> 6) * 66 : colBase;

    STAGE_B(lsB[0], 0);
    STAGE_A(lsA[0], 0, 0);

    const int aswz = (lk ^ ((lr >> 1) & 3)) << 3;
    int aoff[4];
#pragma unroll
    for (int mf = 0; mf < 4; ++mf)
        aoff[mf] = (mw * 64 + mf * 16 + lr) * 32 + aswz;

    f32x4 acc[4][4] = {};
    for (int kx = 0; kx < NKX; ++kx) {
        const u16* lb = lsB[kx % 3];
#pragma unroll
        for (int t = 0; t < NT; ++t) {
            const int s = kx * NT + t;
            const bool lastS = (kx == NKX - 1) && (t == NT - 1);
            const bool stgB = (t == 0) && (kx + 1 < NKX);
            if (stgB) STAGE_B(lsB[(kx + 1) % 3], kx + 1);
            if (!lastS) {
                const int t1 = (t + 1 == NT) ? 0 : t + 1;
                const int kx1 = (t + 1 == NT) ? kx + 1 : kx;
                STAGE_A(lsA[(s + 1) % 3], t1, kx1);
            }
            if (lastS) { VMCNT(0); }
            else if (stgB) { if constexpr (MINB == 2) VMCNT(4); else VMCNT(6); }
            else { VMCNT(2); }
            __builtin_amdgcn_s_barrier();
            asm volatile("" ::: "memory");

            const u16* la = lsA[s % 3];
            bf16x8 af[4], bfr[4];
#pragma unroll
            for (int mf = 0; mf < 4; ++mf)
                af[mf] = *(const bf16x8*)(la + aoff[mf]);
            int rb;
            if (PADDED) {
                int dh = t / 3 - 1, dw = t - (t / 3) * 3 - 1;
                rb = (nw + dh + 1) * 66 + dw + 1 + lr;
            } else {
                rb = nw * 64 + lr;
            }
            const int bswz = (lk ^ ((rb >> 1) & 3)) << 3;
#pragma unroll
            for (int nf = 0; nf < 4; ++nf)
                bfr[nf] = *(const bf16x8*)(lb + (rb + nf * 16) * 32 + bswz);
#pragma unroll
            for (int mf = 0; mf < 4; ++mf)
#pragma unroll
                for (int nf = 0; nf < 4; ++nf)
                    acc[mf][nf] = __builtin_amdgcn_mfma_f32_16x16x32_bf16(
                        af[mf], bfr[nf], acc[mf][nf], 0, 0, 0);
        }
    }

#pragma unroll
    for (int mf = 0; mf < 4; ++mf) {
#pragma unroll
        for (int reg = 0; reg < 4; ++reg) {
            int co = rowBase + mw * 64 + mf * 16 + lk * 4 + reg;
            float sc = scale[co], sh = shift[co];
#pragma unroll
            for (int nf = 0; nf < 4; ++nf) {
                int col = colBase + nw * 64 + nf * 16 + lr;
                float y = acc[mf][nf][reg] * sc + sh;
                if (silu) y = y / (1.f + expf(-y));
                Cn[(long)co * 4096 + col] = y;
            }
        }
    }
}

// ---------------- prep kernels ----------------
__global__ __launch_bounds__(256) void prep_w_kernel(
    const float* __restrict__ w_conv, const float* __restrict__ w_up,
    const float* __restrict__ w_enc,
    u16* __restrict__ wT, u16* __restrict__ wupT, u16* __restrict__ wencT)
{
    int gid = blockIdx.x * 256 + threadIdx.x;
    if (gid < 589824) {             // wT[t][co][ci] = w_conv[co][ci][t]
        int t = gid >> 16;
        int co = (gid >> 8) & 255;
        int ci = gid & 255;
        wT[gid] = f2bf(w_conv[(co * 256 + ci) * 9 + t]);
    }
    if (gid < 131072) wupT[gid] = f2bf(w_up[gid]);
    if (gid < 73728) {              // wencT[t][co<64][ci] (zeros co>=36)
        int t = gid >> 13;
        int co = (gid >> 7) & 63;
        int ci = gid & 127;
        wencT[gid] = (co < 36) ? f2bf(w_enc[(co * 128 + ci) * 9 + t]) : (u16)0;
    }
}

__global__ void prep_bn_kernel(const float* __restrict__ bn_conv,
                               const float* __restrict__ b_up,
                               const float* __restrict__ w_l2,
                               float* __restrict__ bnp)
{
    int i = threadIdx.x;            // 256
    float g = bn_conv[i], b = bn_conv[256 + i], m = bn_conv[512 + i], v = bn_conv[768 + i];
    float sc = g * rsqrtf(v + EPS);
    bnp[i] = sc;
    bnp[256 + i] = b - m * sc;
    bnp[768 + i] = b_up[i];
    if (i < 8) {                    // c2[j] = w_l2[j] . b_up
        float s = 0.f;
        for (int co = 0; co < 256; ++co) s += w_l2[i * 256 + co] * b_up[co];
        bnp[512 + i] = s;
    }
}

__global__ __launch_bounds__(256) void prep_ww2_kernel(
    const float* __restrict__ w_l2, const float* __restrict__ w_up,
    float* __restrict__ ww2)
{
    int ci = blockIdx.x * 256 + threadIdx.x;    // 0..511
    float s[8] = {};
    for (int co = 0; co < 256; ++co) {
        float x = w_up[(long)co * 512 + ci];
#pragma unroll
        for (int j = 0; j < 8; ++j) s[j] += w_l2[j * 256 + co] * x;
    }
#pragma unroll
    for (int j = 0; j < 8; ++j) ww2[j * 512 + ci] = s[j];
}

extern "C" void kernel_launch(void* const* d_in, const int* in_sizes, int n_in,
                              void* d_out, int out_size, void* d_ws, size_t ws_size,
                              hipStream_t stream)
{
    const float* input1 = (const float*)d_in[0];
    const float* input2 = (const float*)d_in[1];
    const float* w_down = (const float*)d_in[2];
    const float* b_down = (const float*)d_in[3];
    const float* w_enc  = (const float*)d_in[4];
    const float* b_enc  = (const float*)d_in[5];
    const float* w_up   = (const float*)d_in[6];
    const float* b_up   = (const float*)d_in[7];
    const float* w_l1   = (const float*)d_in[8];
    const float* bn_l1  = (const float*)d_in[9];
    const float* w_l2   = (const float*)d_in[10];
    const float* bn_l2  = (const float*)d_in[11];
    const float* w_wl   = (const float*)d_in[12];
    const float* b_wl   = (const float*)d_in[13];
    const float* w_conv = (const float*)d_in[14];
    const float* bn_conv= (const float*)d_in[15];
    float* out = (float*)d_out;

    // workspace layout (float units). ~37 MB total.
    float* ws     = (float*)d_ws;
    float* ktTf   = ws;                      //   591,872 f : ktT bf16 [n][1156][128]
    float* wencTf = ktTf + 591872;           //    36,864 f
    float* kt2    = wencTf + 36864;          //   294,912 f
    float* maskb  = kt2 + 294912;            //   294,912 f
    float* in2Tf  = maskb + 294912;          // 2,097,152 f : in2T bf16 [n][1024][512]
    float* zbfTf  = in2Tf + 2097152;         // 1,048,576 f : zbfT bf16 [n][1024][256]
    float* zwT    = zbfTf + 1048576;         //    65,536 f : [n][1024][8] fp32
    float* ftbf   = zwT + 65536;             // 4,460,544 f : fusedT bf16 [n][4356][256]
    float* wTf    = ftbf + 4460544;          //   294,912 f
    float* wupTf  = wTf + 294912;            //    65,536 f
    float* ww2    = wupTf + 65536;           //     4,096 f
    float* bnp    = ww2 + 4096;              //     1,024 f
    u16* ktT      = (u16*)ktTf;
    u16* wencT    = (u16*)wencTf;
    u16* in2T     = (u16*)in2Tf;
    u16* zbfT     = (u16*)zbfTf;
    u16* ftb      = (u16*)ftbf;
    u16* wT       = (u16*)wTf;
    u16* wupT     = (u16*)wupTf;

    // prep (independent)
    prep_w_kernel<<<dim3(2304), 256, 0, stream>>>(w_conv, w_up, w_enc, wT, wupT, wencT);
    prep_bn_kernel<<<dim3(1), 256, 0, stream>>>(bn_conv, b_up, w_l2, bnp);
    prep_ww2_kernel<<<dim3(2), 256, 0, stream>>>(w_l2, w_up, ww2);
    border_zero_kernel<<<dim3(260), 256, 0, stream>>>(ftb);

    // mask pipeline
    hipMemsetAsync(ktT, 0, 8L * 1156 * 128 * 2, stream);
    down_gemm_kernel<<<dim3(16, 2, 8), 256, 0, stream>>>(w_down, input2, b_down, ktT);
    enc_mfma_kernel<<<dim3(64, 8), 64, 0, stream>>>(wencT, ktT, b_enc, kt2);
    mask_softmax_kernel<<<dim3(128), 256, 0, stream>>>(kt2, maskb);

    // z pipeline (commuted up-conv at low res)
    in2t_kernel<<<dim3(32, 8), 256, 0, stream>>>(input2, in2T);
    zgemm_kernel<<<dim3(8, 2, 8), 256, 0, stream>>>(wupT, in2T, zbfT);
    zw_kernel<<<dim3(4, 8), 256, 0, stream>>>(input2, ww2, zwT);

    // CARAFE + level attention + blend -> fusedT
    carafe_fuse_kernel<<<dim3(128, 8), 256, 0, stream>>>(
        input1, zbfT, zwT, maskb, bnp, w_l1, bn_l1, bn_l2, w_wl, b_wl, ftb);

    // K7: final conv (m97+T4, 9-tap) + BN + SiLU
    gemm_m97_kernel<256, 9, true><<<dim3(32, 2, 8), 256, 0, stream>>>(
        wT, ftb, bnp, bnp + 256, out, 4356L * 256, 256L * 4096, 1);
}

// Round 13
// 229.273 us; speedup vs baseline: 1.1324x; 1.1324x over previous
//
#include <hip/hip_runtime.h>
#include <math.h>

// ASFF_2: N=8, C1=256, C2=512, H=64, W=64, low-res 32x32.
// CARAFE-commutation: u = w_up@CARAFE(in2)+b_up == CARAFE(z)+b_up with
// z = w_up@in2 (low-res GEMM, 4x fewer FLOPs); v2 = w_l2@u == CARAFE(zw)+c2,
// zw = w_l2@z (computed in-block from the staged z tile), c2 = w_l2@b_up.
//  K1 down_gemm: ktT = bf16T(w_down @ input2 + b_down)  [N,34*34,128] padded
//  K2 enc_mfma -> kt2 ; K3 softmax -> maskb
//  in2t: input2 -> in2T bf16 [n][1024][512]
//  zgemm: zbfT = bf16(w_up @ in2T) [n][1024][256]   (m97+T4 structure)
//  carafe_fuse: zw in-block; u=CARAFE(z)+b_up; lw0 softmax; blend -> fusedT
//  K7 m97+T4 9-tap conv GEMM + BN + SiLU -> out

#define EPS 1e-5f
typedef unsigned short u16;
typedef __attribute__((ext_vector_type(8))) __bf16 bf16x8;
typedef __attribute__((ext_vector_type(4))) float f32x4;

#define VMCNT(N) asm volatile("s_waitcnt vmcnt(" #N ")" ::: "memory")

__device__ inline u16 f2bf(float x) {
    union { float f; unsigned u; } v; v.f = x;
    unsigned r = v.u + 0x7FFF + ((v.u >> 16) & 1);
    return (u16)(r >> 16);
}
__device__ inline float bf2f(u16 x) {
    union { unsigned u; float f; } v; v.u = (unsigned)x << 16; return v.f;
}

// ---------------- K1: fp32 tiled GEMM, bf16-transposed-padded output ----------------
__global__ __launch_bounds__(256) void down_gemm_kernel(
    const float* __restrict__ A, const float* __restrict__ B,
    const float* __restrict__ bias, u16* __restrict__ ktT)
{
    const int n = blockIdx.z;
    const float* Bn = B + (long)n * 512 * 1024;
    __shared__ __align__(16) float As[16][68];
    __shared__ __align__(16) float Bs[16][64];
    const int tid = threadIdx.x;
    const int tcol = tid & 15;
    const int trow = tid >> 4;
    const int rowBase = blockIdx.y * 64;
    const int colBase = blockIdx.x * 64;
    float acc[4][4] = {};
    for (int k0 = 0; k0 < 512; k0 += 16) {
#pragma unroll
        for (int i = 0; i < 4; ++i) {
            int idx = i * 256 + tid;
            int r = idx >> 4, cc = idx & 15;
            As[cc][r] = A[(long)(rowBase + r) * 512 + k0 + cc];
        }
#pragma unroll
        for (int i = 0; i < 4; ++i) {
            int idx = i * 256 + tid;
            int r = idx >> 6, cc = idx & 63;
            Bs[r][cc] = Bn[(long)(k0 + r) * 1024 + colBase + cc];
        }
        __syncthreads();
#pragma unroll
        for (int kk = 0; kk < 16; ++kk) {
            float4 a4 = *reinterpret_cast<const float4*>(&As[kk][trow * 4]);
            float4 b4 = *reinterpret_cast<const float4*>(&Bs[kk][tcol * 4]);
            float a[4] = {a4.x, a4.y, a4.z, a4.w};
            float b[4] = {b4.x, b4.y, b4.z, b4.w};
#pragma unroll
            for (int i = 0; i < 4; ++i)
#pragma unroll
                for (int j = 0; j < 4; ++j)
                    acc[i][j] += a[i] * b[j];
        }
        __syncthreads();
    }
    u16* Kn = ktT + (long)n * 1156 * 128;
#pragma unroll
    for (int i = 0; i < 4; ++i) {
        int ch = rowBase + trow * 4 + i;
        float bv = bias[ch];
#pragma unroll
        for (int j = 0; j < 4; ++j) {
            int p = colBase + tcol * 4 + j;
            int pr = ((p >> 5) + 1) * 34 + (p & 31) + 1;
            Kn[pr * 128 + ch] = f2bf(acc[i][j] + bv);
        }
    }
}

// ---------------- K2: encoder conv as 9-tap shifted MFMA GEMM ----------------
__global__ __launch_bounds__(64) void enc_mfma_kernel(
    const u16* __restrict__ A, const u16* __restrict__ B,
    const float* __restrict__ bias, float* __restrict__ C)
{
    const int n = blockIdx.y;
    const int lane = threadIdx.x;
    const int lr = lane & 15, lk = lane >> 4;
    const int p = blockIdx.x * 16 + lr;
    const int pr = ((p >> 5) + 1) * 34 + (p & 31) + 1;
    const u16* Bn = B + (long)n * 1156 * 128;
    const int bOff = pr * 128 + lk * 8;
    f32x4 acc[3] = {};
    for (int t = 0; t < 9; ++t) {
        const u16* At = A + t * 8192;
        const int btap = ((t / 3 - 1) * 34 + (t % 3 - 1)) * 128;
#pragma unroll
        for (int k0 = 0; k0 < 128; k0 += 32) {
            bf16x8 bf = *(const bf16x8*)(Bn + bOff + btap + k0);
#pragma unroll
            for (int mf = 0; mf < 3; ++mf) {
                bf16x8 af = *(const bf16x8*)(At + (mf * 16 + lr) * 128 + lk * 8 + k0);
                acc[mf] = __builtin_amdgcn_mfma_f32_16x16x32_bf16(af, bf, acc[mf], 0, 0, 0);
            }
        }
    }
    float* Cn = C + (long)n * 36 * 1024;
#pragma unroll
    for (int mf = 0; mf < 3; ++mf)
#pragma unroll
        for (int reg = 0; reg < 4; ++reg) {
            int co = mf * 16 + lk * 4 + reg;
            if (co < 36)
                Cn[(long)co * 1024 + p] = acc[mf][reg] + bias[co];
        }
}

// ---------------- K3: softmax over k=9 ----------------
__global__ __launch_bounds__(256) void mask_softmax_kernel(
    const float* __restrict__ kt2, float* __restrict__ mask)
{
    int gid = blockIdx.x * 256 + threadIdx.x;   // N*1024*4
    int q = gid & 3;
    int p = (gid >> 2) & 1023;
    int n = gid >> 12;
    float s[9];
    float mx = -1e30f;
#pragma unroll
    for (int k = 0; k < 9; ++k) {
        s[k] = kt2[(long)(n * 36 + k * 4 + q) * 1024 + p];
        mx = fmaxf(mx, s[k]);
    }
    float sum = 0.f;
#pragma unroll
    for (int k = 0; k < 9; ++k) { s[k] = expf(s[k] - mx); sum += s[k]; }
    float inv = 1.f / sum;
    float* mp = mask + (long)(n * 1024 + p) * 36 + q;
#pragma unroll
    for (int k = 0; k < 9; ++k) mp[k * 4] = s[k] * inv;
}

// ---------------- in2t: transpose-cast input2 [512][1024] -> in2T bf16 [q][512] ----------------
__global__ __launch_bounds__(256) void in2t_kernel(
    const float* __restrict__ src0, u16* __restrict__ dst)
{
    __shared__ u16 lds[32 * 514];
    const int n = blockIdx.y;
    const int p0 = blockIdx.x * 32;
    const int tid = threadIdx.x;
    {
        const int w = tid & 31;
        const int chunk = tid >> 5;
        const float* src = src0 + (long)n * 512 * 1024 + p0 + w;
        for (int ci = chunk * 64; ci < chunk * 64 + 64; ++ci)
            lds[w * 514 + ci] = f2bf(src[(long)ci * 1024]);
    }
    __syncthreads();
    const int px = tid >> 3;
    const int qd = tid & 7;
    u16* drow = dst + ((long)n * 1024 + p0 + px) * 512;
    const u16* lrow = lds + px * 514;
#pragma unroll
    for (int j = 0; j < 32; ++j) {
        int off = j * 16 + qd * 2;
        *(unsigned*)(drow + off) = *(const unsigned*)(lrow + off);
    }
}

// ---------------- staging macros (shared by zgemm / gemm_m97) ----------------
#define STAGE_A(dstp, t, kx)                                                         \
    {                                                                                \
        const u16* Abase = A + ((long)(t) * 256 + rowBase) * KCC + (kx) * 32;        \
        _Pragma("unroll")                                                            \
        for (int ii = 0; ii < 2; ++ii) {                                             \
            int f = ii * 256 + tid;                                                  \
            int r = f >> 2, uu = f & 3;                                              \
            __builtin_amdgcn_global_load_lds(                                        \
                (const __attribute__((address_space(1))) void*)                      \
                    (Abase + (long)r * KCC + ((uu ^ ((r >> 1) & 3)) << 3)),          \
                (__attribute__((address_space(3))) void*)((dstp) + f * 8),           \
                16, 0, 0);                                                           \
        }                                                                            \
    }

#define STAGE_B(dstp, kx)                                                            \
    {                                                                                \
        const u16* Bbase = Bn + (long)g0 * KCC + (kx) * 32;                          \
        for (int f = tid; f < BUNITS; f += 256) {                                    \
            int r = f >> 2, uu = f & 3;                                              \
            __builtin_amdgcn_global_load_lds(                                        \
                (const __attribute__((address_space(1))) void*)                      \
                    (Bbase + (long)r * KCC + ((uu ^ ((r >> 1) & 3)) << 3)),          \
                (__attribute__((address_space(3))) void*)((dstp) + f * 8),           \
                16, 0, 0);                                                           \
        }                                                                            \
    }

// ---------------- zgemm: zbfT = bf16(w_up @ in2T)  [n][1024][256] ----------------
__global__ __launch_bounds__(256, 2) void zgemm_kernel(
    const u16* __restrict__ A,      // wupT [256][512]
    const u16* __restrict__ B,      // in2T [n][1024][512]
    u16* __restrict__ Z)            // zbfT [n][1024][256]
{
    constexpr int KCC = 512;
    constexpr int BUNITS = 512;
    constexpr int NKX = 16;
    __shared__ __align__(16) u16 lsA[3][128 * 32];
    __shared__ __align__(16) u16 lsB[3][128 * 32];
    const int n = blockIdx.z;
    const u16* Bn = B + (long)n * 1024 * 512;
    const int tid = threadIdx.x;
    const int lane = tid & 63;
    const int wid = tid >> 6;
    const int mw = wid >> 1, nw = wid & 1;
    const int lr = lane & 15, lk = lane >> 4;
    const int rowBase = blockIdx.y * 128;
    const int colBase = blockIdx.x * 128;
    const int g0 = colBase;

    STAGE_B(lsB[0], 0);
    STAGE_A(lsA[0], 0, 0);

    const int aswz = (lk ^ ((lr >> 1) & 3)) << 3;
    int aoff[4];
#pragma unroll
    for (int mf = 0; mf < 4; ++mf)
        aoff[mf] = (mw * 64 + mf * 16 + lr) * 32 + aswz;

    f32x4 acc[4][4] = {};
    for (int kx = 0; kx < NKX; ++kx) {
        const bool lastS = (kx == NKX - 1);
        if (!lastS) {
            STAGE_B(lsB[(kx + 1) % 3], kx + 1);
            STAGE_A(lsA[(kx + 1) % 3], 0, kx + 1);
        }
        if (lastS) { VMCNT(0); } else { VMCNT(4); }
        __builtin_amdgcn_s_barrier();
        asm volatile("" ::: "memory");
        const u16* la = lsA[kx % 3];
        const u16* lb = lsB[kx % 3];
        bf16x8 af[4], bfr[4];
#pragma unroll
        for (int mf = 0; mf < 4; ++mf)
            af[mf] = *(const bf16x8*)(la + aoff[mf]);
        const int rb = nw * 64 + lr;
        const int bswz = (lk ^ ((rb >> 1) & 3)) << 3;
#pragma unroll
        for (int nf = 0; nf < 4; ++nf)
            bfr[nf] = *(const bf16x8*)(lb + (rb + nf * 16) * 32 + bswz);
#pragma unroll
        for (int mf = 0; mf < 4; ++mf)
#pragma unroll
            for (int nf = 0; nf < 4; ++nf)
                acc[mf][nf] = __builtin_amdgcn_mfma_f32_16x16x32_bf16(
                    af[mf], bfr[nf], acc[mf][nf], 0, 0, 0);
    }

    u16* Zn = Z + (long)n * 1024 * 256;
#pragma unroll
    for (int mf = 0; mf < 4; ++mf) {
        const int co0 = rowBase + mw * 64 + mf * 16 + lk * 4;
#pragma unroll
        for (int nf = 0; nf < 4; ++nf) {
            const int col = colBase + nw * 64 + nf * 16 + lr;
            unsigned lo = (unsigned)f2bf(acc[mf][nf][0]) |
                          ((unsigned)f2bf(acc[mf][nf][1]) << 16);
            unsigned hi = (unsigned)f2bf(acc[mf][nf][2]) |
                          ((unsigned)f2bf(acc[mf][nf][3]) << 16);
            *(uint2*)(Zn + (long)col * 256 + co0) = make_uint2(lo, hi);
        }
    }
}

// ---------------- border_zero: zero the 66x66 pad ring of fusedT ----------------
__global__ __launch_bounds__(256) void border_zero_kernel(u16* __restrict__ ftb)
{
    int gid = blockIdx.x * 256 + threadIdx.x;   // 8 * 260 * 32 uint4
    if (gid >= 8 * 260 * 32) return;
    int n = gid / (260 * 32);
    int rem = gid - n * (260 * 32);
    int r = rem >> 5;
    int i = rem & 31;
    int h, w;
    if (r < 66)       { h = 0;  w = r; }
    else if (r < 132) { h = 65; w = r - 66; }
    else { int j = r - 132; h = 1 + (j >> 1); w = (j & 1) * 65; }
    long prow = (long)h * 66 + w;
    uint4* dst = (uint4*)(ftb + (long)n * 4356 * 256 + prow * 256) + i;
    *dst = make_uint4(0, 0, 0, 0);
}

// ---------------- carafe_fuse: zw in-block, u=CARAFE(z)+b_up, lw0, blend -> fusedT ----------------
// Block: 32 hi-res px. LDS z-tile 3x18 lowres px x 256ch bf16 (stride 264 for uint4).
// red reduction scratch UNIONed with lds2 output staging (disjoint in time).
__global__ __launch_bounds__(256) void carafe_fuse_kernel(
    const float* __restrict__ i1g, const u16* __restrict__ zbfT,
    const float* __restrict__ maskb,
    const float* __restrict__ bnp,          // 512..519 c2, 768.. b_up
    const float* __restrict__ w_l1, const float* __restrict__ w_l2,
    const float* __restrict__ bn_l1, const float* __restrict__ bn_l2,
    const float* __restrict__ w_wl, const float* __restrict__ b_wl,
    u16* __restrict__ dst)
{
    __shared__ __align__(16) u16 zbf[54 * 264];     // 27.8 KB
    __shared__ float zwl[54 * 8];                   // 1.7 KB
    __shared__ float mlds[16 * 36];                 // 2.3 KB
    __shared__ float lw0s[32];
    __shared__ __align__(16) unsigned char uscr[32 * 264 * 2];  // 16.5 KB union
    float* red = (float*)uscr;                      // [8][32][8]
    u16* lds2 = (u16*)uscr;                         // [32][264]
    const int n = blockIdx.y;
    const int h = blockIdx.x >> 1;
    const int w0 = (blockIdx.x & 1) << 5;
    const int hq = h >> 1;
    const int wq0 = w0 >> 1;
    const int tid = threadIdx.x;

    // stage z tile (uint4 = 8ch), zero-filled OOB
    for (int idx = tid; idx < 54 * 32; idx += 256) {
        int px = idx >> 5, unit = idx & 31;
        int r = px / 18, c = px - r * 18;
        int gr = hq - 1 + r, gc = wq0 - 1 + c;
        uint4 v = make_uint4(0u, 0u, 0u, 0u);
        if (gr >= 0 && gr < 32 && gc >= 0 && gc < 32)
            v = *(const uint4*)(zbfT + ((long)n * 1024 + gr * 32 + gc) * 256 + unit * 8);
        *(uint4*)(zbf + px * 264 + unit * 8) = v;
    }
    for (int idx = tid; idx < 576; idx += 256)
        mlds[idx] = maskb[((long)n * 1024 + hq * 32 + wq0) * 36 + idx];
    __syncthreads();

    const int w = tid & 31;
    const int chunk = tid >> 5;
    const int p = (h << 6) + w0 + w;
    const float* i1 = i1g + ((long)n * 256 * 4096) + p;
    {   // pass1: v1 partials -> red (union region)
        float s1[8] = {};
        for (int ci = chunk * 32; ci < chunk * 32 + 32; ++ci) {
            float x1 = i1[(long)ci * 4096];
#pragma unroll
            for (int j = 0; j < 8; ++j) s1[j] += w_l1[j * 256 + ci] * x1;
        }
#pragma unroll
        for (int j = 0; j < 8; ++j) red[(chunk * 32 + w) * 8 + j] = s1[j];
    }
    // zwl: zw[px][j] = w_l2[j] . z[px]  (from staged zbf)
    for (int c = tid; c < 432; c += 256) {
        int px = c >> 3, j = c & 7;
        const u16* zp = zbf + px * 264;
        const float* wl = w_l2 + j * 256;
        float s = 0.f;
        for (int ci = 0; ci < 256; ci += 8) {
            uint4 vz = *(const uint4*)(zp + ci);
            float4 wa = *(const float4*)(wl + ci);
            float4 wb = *(const float4*)(wl + ci + 4);
            s += wa.x * bf2f((u16)(vz.x & 0xffff)) + wa.y * bf2f((u16)(vz.x >> 16))
               + wa.z * bf2f((u16)(vz.y & 0xffff)) + wa.w * bf2f((u16)(vz.y >> 16))
               + wb.x * bf2f((u16)(vz.z & 0xffff)) + wb.y * bf2f((u16)(vz.z >> 16))
               + wb.z * bf2f((u16)(vz.w & 0xffff)) + wb.w * bf2f((u16)(vz.w >> 16));
        }
        zwl[px * 8 + j] = s;
    }
    __syncthreads();
    {   // reduce red over 8 chunks: 256 cells
        int px = tid >> 3, j = tid & 7;
        float s = 0.f;
#pragma unroll
        for (int o = 0; o < 8; ++o) s += red[(o * 32 + px) * 8 + j];
        red[px * 8 + j] = s;
    }
    __syncthreads();
    if (tid < 32) {
        const int wp = w0 + tid;
        const int wqm = (wp >> 1) - wq0;        // 0..15
        const int q = ((h & 1) << 1) | (wp & 1);
        float m9[9];
#pragma unroll
        for (int k = 0; k < 9; ++k) m9[k] = mlds[wqm * 36 + k * 4 + q];
        float v[16];
#pragma unroll
        for (int j = 0; j < 8; ++j) v[j] = red[tid * 8 + j];
#pragma unroll
        for (int j = 0; j < 8; ++j) v[8 + j] = bnp[512 + j];   // c2
#pragma unroll
        for (int k = 0; k < 9; ++k) {
            int dh = k / 3 - 1, dw = k - (k / 3) * 3 - 1;
            const float* zp = zwl + ((1 + dh) * 18 + wqm + 1 + dw) * 8;
            float mk = m9[k];
#pragma unroll
            for (int j = 0; j < 8; ++j) v[8 + j] += mk * zp[j];
        }
        float z0 = b_wl[0], z1 = b_wl[1];
#pragma unroll
        for (int j = 0; j < 8; ++j) {
            float g = bn_l1[j], b = bn_l1[8 + j], m = bn_l1[16 + j], va = bn_l1[24 + j];
            float y = (v[j] - m) * (g * rsqrtf(va + EPS)) + b;
            float sv = y / (1.f + expf(-y));
            z0 += w_wl[j] * sv;
            z1 += w_wl[16 + j] * sv;
            g = bn_l2[j]; b = bn_l2[8 + j]; m = bn_l2[16 + j]; va = bn_l2[24 + j];
            y = (v[8 + j] - m) * (g * rsqrtf(va + EPS)) + b;
            sv = y / (1.f + expf(-y));
            z0 += w_wl[8 + j] * sv;
            z1 += w_wl[24 + j] * sv;
        }
        lw0s[tid] = 1.f / (1.f + expf(z1 - z0));
    }
    __syncthreads();
    {   // pass2: u = CARAFE(z)+b_up ; blend ; bf16 into lds2 (overwrites red region)
        const float lw = lw0s[w], lw1 = 1.f - lw;
        const int wp = w0 + w;
        const int wqm = (wp >> 1) - wq0;
        const int q = ((h & 1) << 1) | (wp & 1);
        float m9[9];
#pragma unroll
        for (int k = 0; k < 9; ++k) m9[k] = mlds[wqm * 36 + k * 4 + q];
        for (int ci = chunk * 32; ci < chunk * 32 + 32; ci += 8) {
            float uu[8];
            {
                float4 ba = *(const float4*)(bnp + 768 + ci);
                float4 bb = *(const float4*)(bnp + 768 + ci + 4);
                uu[0] = ba.x; uu[1] = ba.y; uu[2] = ba.z; uu[3] = ba.w;
                uu[4] = bb.x; uu[5] = bb.y; uu[6] = bb.z; uu[7] = bb.w;
            }
#pragma unroll
            for (int k = 0; k < 9; ++k) {
                int dh = k / 3 - 1, dw = k - (k / 3) * 3 - 1;
                uint4 vz = *(const uint4*)(zbf + ((1 + dh) * 18 + wqm + 1 + dw) * 264 + ci);
                float mk = m9[k];
                uu[0] += mk * bf2f((u16)(vz.x & 0xffff));
                uu[1] += mk * bf2f((u16)(vz.x >> 16));
                uu[2] += mk * bf2f((u16)(vz.y & 0xffff));
                uu[3] += mk * bf2f((u16)(vz.y >> 16));
                uu[4] += mk * bf2f((u16)(vz.z & 0xffff));
                uu[5] += mk * bf2f((u16)(vz.z >> 16));
                uu[6] += mk * bf2f((u16)(vz.w & 0xffff));
                uu[7] += mk * bf2f((u16)(vz.w >> 16));
            }
            unsigned o0 = (unsigned)f2bf(i1[(long)ci * 4096] * lw + uu[0] * lw1)
                        | ((unsigned)f2bf(i1[(long)(ci + 1) * 4096] * lw + uu[1] * lw1) << 16);
            unsigned o1 = (unsigned)f2bf(i1[(long)(ci + 2) * 4096] * lw + uu[2] * lw1)
                        | ((unsigned)f2bf(i1[(long)(ci + 3) * 4096] * lw + uu[3] * lw1) << 16);
            unsigned o2 = (unsigned)f2bf(i1[(long)(ci + 4) * 4096] * lw + uu[4] * lw1)
                        | ((unsigned)f2bf(i1[(long)(ci + 5) * 4096] * lw + uu[5] * lw1) << 16);
            unsigned o3 = (unsigned)f2bf(i1[(long)(ci + 6) * 4096] * lw + uu[6] * lw1)
                        | ((unsigned)f2bf(i1[(long)(ci + 7) * 4096] * lw + uu[7] * lw1) << 16);
            *(uint4*)(lds2 + w * 264 + ci) = make_uint4(o0, o1, o2, o3);
        }
    }
    __syncthreads();
    {   // transposed padded write
        const int px = tid >> 3, qd = tid & 7;
        const int pg = (h << 6) + w0 + px;
        long prow = (long)((pg >> 6) + 1) * 66 + (pg & 63) + 1;
        u16* drow = dst + (long)n * 4356 * 256 + prow * 256;
        const u16* lrow = lds2 + px * 264;
#pragma unroll
        for (int j = 0; j < 16; ++j) {
            int off = j * 16 + qd * 2;
            *(unsigned*)(drow + off) = *(const unsigned*)(lrow + off);
        }
    }
}

// ---------------- K7: m97+T4 GEMM — triple-buf LDS, counted vmcnt ----------------
template<int KCC, int NT, bool PADDED>
__global__ __launch_bounds__(256, 2) void gemm_m97_kernel(
    const u16* __restrict__ A,      // [NT][256][KCC] bf16
    const u16* __restrict__ B,      // per image [rows][KCC] bf16
    const float* __restrict__ scale, const float* __restrict__ shift,
    float* __restrict__ C, long strideB, long strideC, int silu)
{
    constexpr int RROWS = PADDED ? 264 : 128;
    constexpr int BUNITS = RROWS * 4;
    constexpr int NKX = KCC / 32;
    constexpr int MINB = BUNITS / 256;
    __shared__ __align__(16) u16 lsA[3][128 * 32];
    __shared__ __align__(16) u16 lsB[3][RROWS * 32];
    const int n = blockIdx.z;
    const u16* Bn = B + (long)n * strideB;
    float* Cn = C + (long)n * strideC;
    const int tid = threadIdx.x;
    const int lane = tid & 63;
    const int wid = tid >> 6;
    const int mw = wid >> 1, nw = wid & 1;
    const int lr = lane & 15, lk = lane >> 4;
    const int rowBase = blockIdx.y * 128;
    const int colBase = blockIdx.x * 128;
    const int g0 = PADDED ? (colBase >> 6) * 66 : colBase;

    STAGE_B(lsB[0], 0);
    STAGE_A(lsA[0], 0, 0);

    const int aswz = (lk ^ ((lr >> 1) & 3)) << 3;
    int aoff[4];
#pragma unroll
    for (int mf = 0; mf < 4; ++mf)
        aoff[mf] = (mw * 64 + mf * 16 + lr) * 32 + aswz;

    f32x4 acc[4][4] = {};
    for (int kx = 0; kx < NKX; ++kx) {
        const u16* lb = lsB[kx % 3];
#pragma unroll
        for (int t = 0; t < NT; ++t) {
            const int s = kx * NT + t;
            const bool lastS = (kx == NKX - 1) && (t == NT - 1);
            const bool stgB = (t == 0) && (kx + 1 < NKX);
            if (stgB) STAGE_B(lsB[(kx + 1) % 3], kx + 1);
            if (!lastS) {
                const int t1 = (t + 1 == NT) ? 0 : t + 1;
                const int kx1 = (t + 1 == NT) ? kx + 1 : kx;
                STAGE_A(lsA[(s + 1) % 3], t1, kx1);
            }
            if (lastS) { VMCNT(0); }
            else if (stgB) { if constexpr (MINB == 2) VMCNT(4); else VMCNT(6); }
            else { VMCNT(2); }
            __builtin_amdgcn_s_barrier();
            asm volatile("" ::: "memory");

            const u16* la = lsA[s % 3];
            bf16x8 af[4], bfr[4];
#pragma unroll
            for (int mf = 0; mf < 4; ++mf)
                af[mf] = *(const bf16x8*)(la + aoff[mf]);
            int rb;
            if (PADDED) {
                int dh = t / 3 - 1, dw = t - (t / 3) * 3 - 1;
                rb = (nw + dh + 1) * 66 + dw + 1 + lr;
            } else {
                rb = nw * 64 + lr;
            }
            const int bswz = (lk ^ ((rb >> 1) & 3)) << 3;
#pragma unroll
            for (int nf = 0; nf < 4; ++nf)
                bfr[nf] = *(const bf16x8*)(lb + (rb + nf * 16) * 32 + bswz);
#pragma unroll
            for (int mf = 0; mf < 4; ++mf)
#pragma unroll
                for (int nf = 0; nf < 4; ++nf)
                    acc[mf][nf] = __builtin_amdgcn_mfma_f32_16x16x32_bf16(
                        af[mf], bfr[nf], acc[mf][nf], 0, 0, 0);
        }
    }

#pragma unroll
    for (int mf = 0; mf < 4; ++mf) {
#pragma unroll
        for (int reg = 0; reg < 4; ++reg) {
            int co = rowBase + mw * 64 + mf * 16 + lk * 4 + reg;
            float sc = scale[co], sh = shift[co];
#pragma unroll
            for (int nf = 0; nf < 4; ++nf) {
                int col = colBase + nw * 64 + nf * 16 + lr;
                float y = acc[mf][nf][reg] * sc + sh;
                if (silu) y = y / (1.f + expf(-y));
                Cn[(long)co * 4096 + col] = y;
            }
        }
    }
}

// ---------------- prep kernels ----------------
__global__ __launch_bounds__(256) void prep_w_kernel(
    const float* __restrict__ w_conv, const float* __restrict__ w_up,
    const float* __restrict__ w_enc,
    u16* __restrict__ wT, u16* __restrict__ wupT, u16* __restrict__ wencT)
{
    int gid = blockIdx.x * 256 + threadIdx.x;
    if (gid < 589824) {             // wT[t][co][ci] = w_conv[co][ci][t]
        int t = gid >> 16;
        int co = (gid >> 8) & 255;
        int ci = gid & 255;
        wT[gid] = f2bf(w_conv[(co * 256 + ci) * 9 + t]);
    }
    if (gid < 131072) wupT[gid] = f2bf(w_up[gid]);
    if (gid < 73728) {              // wencT[t][co<64][ci] (zeros co>=36)
        int t = gid >> 13;
        int co = (gid >> 7) & 63;
        int ci = gid & 127;
        wencT[gid] = (co < 36) ? f2bf(w_enc[(co * 128 + ci) * 9 + t]) : (u16)0;
    }
}

__global__ void prep_bn_kernel(const float* __restrict__ bn_conv,
                               const float* __restrict__ b_up,
                               const float* __restrict__ w_l2,
                               float* __restrict__ bnp)
{
    int i = threadIdx.x;            // 256
    float g = bn_conv[i], b = bn_conv[256 + i], m = bn_conv[512 + i], v = bn_conv[768 + i];
    float sc = g * rsqrtf(v + EPS);
    bnp[i] = sc;
    bnp[256 + i] = b - m * sc;
    bnp[768 + i] = b_up[i];
    if (i < 8) {                    // c2[j] = w_l2[j] . b_up
        float s = 0.f;
        for (int co = 0; co < 256; ++co) s += w_l2[i * 256 + co] * b_up[co];
        bnp[512 + i] = s;
    }
}

extern "C" void kernel_launch(void* const* d_in, const int* in_sizes, int n_in,
                              void* d_out, int out_size, void* d_ws, size_t ws_size,
                              hipStream_t stream)
{
    const float* input1 = (const float*)d_in[0];
    const float* input2 = (const float*)d_in[1];
    const float* w_down = (const float*)d_in[2];
    const float* b_down = (const float*)d_in[3];
    const float* w_enc  = (const float*)d_in[4];
    const float* b_enc  = (const float*)d_in[5];
    const float* w_up   = (const float*)d_in[6];
    const float* b_up   = (const float*)d_in[7];
    const float* w_l1   = (const float*)d_in[8];
    const float* bn_l1  = (const float*)d_in[9];
    const float* w_l2   = (const float*)d_in[10];
    const float* bn_l2  = (const float*)d_in[11];
    const float* w_wl   = (const float*)d_in[12];
    const float* b_wl   = (const float*)d_in[13];
    const float* w_conv = (const float*)d_in[14];
    const float* bn_conv= (const float*)d_in[15];
    float* out = (float*)d_out;

    // workspace layout (float units). ~37 MB total.
    float* ws     = (float*)d_ws;
    float* ktTf   = ws;                      //   591,872 f : ktT bf16 [n][1156][128]
    float* wencTf = ktTf + 591872;           //    36,864 f
    float* kt2    = wencTf + 36864;          //   294,912 f
    float* maskb  = kt2 + 294912;            //   294,912 f
    float* in2Tf  = maskb + 294912;          // 2,097,152 f : in2T bf16 [n][1024][512]
    float* zbfTf  = in2Tf + 2097152;         // 1,048,576 f : zbfT bf16 [n][1024][256]
    float* ftbf   = zbfTf + 1048576;         // 4,460,544 f : fusedT bf16 [n][4356][256]
    float* wTf    = ftbf + 4460544;          //   294,912 f
    float* wupTf  = wTf + 294912;            //    65,536 f
    float* bnp    = wupTf + 65536;           //     1,024 f
    u16* ktT      = (u16*)ktTf;
    u16* wencT    = (u16*)wencTf;
    u16* in2T     = (u16*)in2Tf;
    u16* zbfT     = (u16*)zbfTf;
    u16* ftb      = (u16*)ftbf;
    u16* wT       = (u16*)wTf;
    u16* wupT     = (u16*)wupTf;

    // prep (independent)
    prep_w_kernel<<<dim3(2304), 256, 0, stream>>>(w_conv, w_up, w_enc, wT, wupT, wencT);
    prep_bn_kernel<<<dim3(1), 256, 0, stream>>>(bn_conv, b_up, w_l2, bnp);
    border_zero_kernel<<<dim3(260), 256, 0, stream>>>(ftb);

    // mask pipeline
    hipMemsetAsync(ktT, 0, 8L * 1156 * 128 * 2, stream);
    down_gemm_kernel<<<dim3(16, 2, 8), 256, 0, stream>>>(w_down, input2, b_down, ktT);
    enc_mfma_kernel<<<dim3(64, 8), 64, 0, stream>>>(wencT, ktT, b_enc, kt2);
    mask_softmax_kernel<<<dim3(128), 256, 0, stream>>>(kt2, maskb);

    // z pipeline (commuted up-conv at low res)
    in2t_kernel<<<dim3(32, 8), 256, 0, stream>>>(input2, in2T);
    zgemm_kernel<<<dim3(8, 2, 8), 256, 0, stream>>>(wupT, in2T, zbfT);

    // CARAFE + level attention + blend -> fusedT
    carafe_fuse_kernel<<<dim3(128, 8), 256, 0, stream>>>(
        input1, zbfT, maskb, bnp, w_l1, w_l2, bn_l1, bn_l2, w_wl, b_wl, ftb);

    // K7: final conv (m97+T4, 9-tap) + BN + SiLU
    gemm_m97_kernel<256, 9, true><<<dim3(32, 2, 8), 256, 0, stream>>>(
        wT, ftb, bnp, bnp + 256, out, 4356L * 256, 256L * 4096, 1);
}

// Round 14
// 188.512 us; speedup vs baseline: 1.3773x; 1.2162x over previous
//
#include <hip/hip_runtime.h>
#include <math.h>

// ASFF_2: N=8, C1=256, C2=512, H=64, W=64, low-res 32x32.
// CARAFE-commutation: u = CARAFE(z)+b_up with z = w_up@in2 (low-res GEMM);
// v2 = CARAFE(zw)+c2 with zw = w_l2@z, c2 = w_l2@b_up.
//  K1 down_gemm -> ktT ; K2 enc_mfma -> kt2 ; K3 softmax -> maskb
//  in2t: input2 -> in2T bf16 [n][1024][512]
//  zgemm: zbfT = bf16(w_up @ in2T) [n][1024][256]   (m97+T4)
//  zw: zwT[n][1024][8] = w_l2 @ z   (wave-per-pixel butterfly)
//  fuse_weights: v1 = w_l1@i1, v2 = CARAFE(zw)+c2 -> lw0[n][4096]
//  carafe_blend: u=CARAFE(z)+b_up, blend with i1 -> fusedT bf16 [66x66][256]
//  K7 m97+T4 9-tap conv GEMM + BN + SiLU -> out

#define EPS 1e-5f
typedef unsigned short u16;
typedef __attribute__((ext_vector_type(8))) __bf16 bf16x8;
typedef __attribute__((ext_vector_type(4))) float f32x4;

#define VMCNT(N) asm volatile("s_waitcnt vmcnt(" #N ")" ::: "memory")

__device__ inline u16 f2bf(float x) {
    union { float f; unsigned u; } v; v.f = x;
    unsigned r = v.u + 0x7FFF + ((v.u >> 16) & 1);
    return (u16)(r >> 16);
}
__device__ inline float bf2f(u16 x) {
    union { unsigned u; float f; } v; v.u = (unsigned)x << 16; return v.f;
}

// ---------------- K1: fp32 tiled GEMM, bf16-transposed-padded output ----------------
__global__ __launch_bounds__(256) void down_gemm_kernel(
    const float* __restrict__ A, const float* __restrict__ B,
    const float* __restrict__ bias, u16* __restrict__ ktT)
{
    const int n = blockIdx.z;
    const float* Bn = B + (long)n * 512 * 1024;
    __shared__ __align__(16) float As[16][68];
    __shared__ __align__(16) float Bs[16][64];
    const int tid = threadIdx.x;
    const int tcol = tid & 15;
    const int trow = tid >> 4;
    const int rowBase = blockIdx.y * 64;
    const int colBase = blockIdx.x * 64;
    float acc[4][4] = {};
    for (int k0 = 0; k0 < 512; k0 += 16) {
#pragma unroll
        for (int i = 0; i < 4; ++i) {
            int idx = i * 256 + tid;
            int r = idx >> 4, cc = idx & 15;
            As[cc][r] = A[(long)(rowBase + r) * 512 + k0 + cc];
        }
#pragma unroll
        for (int i = 0; i < 4; ++i) {
            int idx = i * 256 + tid;
            int r = idx >> 6, cc = idx & 63;
            Bs[r][cc] = Bn[(long)(k0 + r) * 1024 + colBase + cc];
        }
        __syncthreads();
#pragma unroll
        for (int kk = 0; kk < 16; ++kk) {
            float4 a4 = *reinterpret_cast<const float4*>(&As[kk][trow * 4]);
            float4 b4 = *reinterpret_cast<const float4*>(&Bs[kk][tcol * 4]);
            float a[4] = {a4.x, a4.y, a4.z, a4.w};
            float b[4] = {b4.x, b4.y, b4.z, b4.w};
#pragma unroll
            for (int i = 0; i < 4; ++i)
#pragma unroll
                for (int j = 0; j < 4; ++j)
                    acc[i][j] += a[i] * b[j];
        }
        __syncthreads();
    }
    u16* Kn = ktT + (long)n * 1156 * 128;
#pragma unroll
    for (int i = 0; i < 4; ++i) {
        int ch = rowBase + trow * 4 + i;
        float bv = bias[ch];
#pragma unroll
        for (int j = 0; j < 4; ++j) {
            int p = colBase + tcol * 4 + j;
            int pr = ((p >> 5) + 1) * 34 + (p & 31) + 1;
            Kn[pr * 128 + ch] = f2bf(acc[i][j] + bv);
        }
    }
}

// ---------------- K2: encoder conv as 9-tap shifted MFMA GEMM ----------------
__global__ __launch_bounds__(64) void enc_mfma_kernel(
    const u16* __restrict__ A, const u16* __restrict__ B,
    const float* __restrict__ bias, float* __restrict__ C)
{
    const int n = blockIdx.y;
    const int lane = threadIdx.x;
    const int lr = lane & 15, lk = lane >> 4;
    const int p = blockIdx.x * 16 + lr;
    const int pr = ((p >> 5) + 1) * 34 + (p & 31) + 1;
    const u16* Bn = B + (long)n * 1156 * 128;
    const int bOff = pr * 128 + lk * 8;
    f32x4 acc[3] = {};
    for (int t = 0; t < 9; ++t) {
        const u16* At = A + t * 8192;
        const int btap = ((t / 3 - 1) * 34 + (t % 3 - 1)) * 128;
#pragma unroll
        for (int k0 = 0; k0 < 128; k0 += 32) {
            bf16x8 bf = *(const bf16x8*)(Bn + bOff + btap + k0);
#pragma unroll
            for (int mf = 0; mf < 3; ++mf) {
                bf16x8 af = *(const bf16x8*)(At + (mf * 16 + lr) * 128 + lk * 8 + k0);
                acc[mf] = __builtin_amdgcn_mfma_f32_16x16x32_bf16(af, bf, acc[mf], 0, 0, 0);
            }
        }
    }
    float* Cn = C + (long)n * 36 * 1024;
#pragma unroll
    for (int mf = 0; mf < 3; ++mf)
#pragma unroll
        for (int reg = 0; reg < 4; ++reg) {
            int co = mf * 16 + lk * 4 + reg;
            if (co < 36)
                Cn[(long)co * 1024 + p] = acc[mf][reg] + bias[co];
        }
}

// ---------------- K3: softmax over k=9 ----------------
__global__ __launch_bounds__(256) void mask_softmax_kernel(
    const float* __restrict__ kt2, float* __restrict__ mask)
{
    int gid = blockIdx.x * 256 + threadIdx.x;   // N*1024*4
    int q = gid & 3;
    int p = (gid >> 2) & 1023;
    int n = gid >> 12;
    float s[9];
    float mx = -1e30f;
#pragma unroll
    for (int k = 0; k < 9; ++k) {
        s[k] = kt2[(long)(n * 36 + k * 4 + q) * 1024 + p];
        mx = fmaxf(mx, s[k]);
    }
    float sum = 0.f;
#pragma unroll
    for (int k = 0; k < 9; ++k) { s[k] = expf(s[k] - mx); sum += s[k]; }
    float inv = 1.f / sum;
    float* mp = mask + (long)(n * 1024 + p) * 36 + q;
#pragma unroll
    for (int k = 0; k < 9; ++k) mp[k * 4] = s[k] * inv;
}

// ---------------- in2t: transpose-cast input2 [512][1024] -> in2T bf16 [q][512] ----------------
__global__ __launch_bounds__(256) void in2t_kernel(
    const float* __restrict__ src0, u16* __restrict__ dst)
{
    __shared__ u16 lds[32 * 514];
    const int n = blockIdx.y;
    const int p0 = blockIdx.x * 32;
    const int tid = threadIdx.x;
    {
        const int w = tid & 31;
        const int chunk = tid >> 5;
        const float* src = src0 + (long)n * 512 * 1024 + p0 + w;
        for (int ci = chunk * 64; ci < chunk * 64 + 64; ++ci)
            lds[w * 514 + ci] = f2bf(src[(long)ci * 1024]);
    }
    __syncthreads();
    const int px = tid >> 3;
    const int qd = tid & 7;
    u16* drow = dst + ((long)n * 1024 + p0 + px) * 512;
    const u16* lrow = lds + px * 514;
#pragma unroll
    for (int j = 0; j < 32; ++j) {
        int off = j * 16 + qd * 2;
        *(unsigned*)(drow + off) = *(const unsigned*)(lrow + off);
    }
}

// ---------------- staging macros (shared by zgemm / gemm_m97) ----------------
#define STAGE_A(dstp, t, kx)                                                         \
    {                                                                                \
        const u16* Abase = A + ((long)(t) * 256 + rowBase) * KCC + (kx) * 32;        \
        _Pragma("unroll")                                                            \
        for (int ii = 0; ii < 2; ++ii) {                                             \
            int f = ii * 256 + tid;                                                  \
            int r = f >> 2, uu = f & 3;                                              \
            __builtin_amdgcn_global_load_lds(                                        \
                (const __attribute__((address_space(1))) void*)                      \
                    (Abase + (long)r * KCC + ((uu ^ ((r >> 1) & 3)) << 3)),          \
                (__attribute__((address_space(3))) void*)((dstp) + f * 8),           \
                16, 0, 0);                                                           \
        }                                                                            \
    }

#define STAGE_B(dstp, kx)                                                            \
    {                                                                                \
        const u16* Bbase = Bn + (long)g0 * KCC + (kx) * 32;                          \
        for (int f = tid; f < BUNITS; f += 256) {                                    \
            int r = f >> 2, uu = f & 3;                                              \
            __builtin_amdgcn_global_load_lds(                                        \
                (const __attribute__((address_space(1))) void*)                      \
                    (Bbase + (long)r * KCC + ((uu ^ ((r >> 1) & 3)) << 3)),          \
                (__attribute__((address_space(3))) void*)((dstp) + f * 8),           \
                16, 0, 0);                                                           \
        }                                                                            \
    }

// ---------------- zgemm: zbfT = bf16(w_up @ in2T)  [n][1024][256] ----------------
__global__ __launch_bounds__(256, 2) void zgemm_kernel(
    const u16* __restrict__ A,      // wupT [256][512]
    const u16* __restrict__ B,      // in2T [n][1024][512]
    u16* __restrict__ Z)            // zbfT [n][1024][256]
{
    constexpr int KCC = 512;
    constexpr int BUNITS = 512;
    constexpr int NKX = 16;
    __shared__ __align__(16) u16 lsA[3][128 * 32];
    __shared__ __align__(16) u16 lsB[3][128 * 32];
    const int n = blockIdx.z;
    const u16* Bn = B + (long)n * 1024 * 512;
    const int tid = threadIdx.x;
    const int lane = tid & 63;
    const int wid = tid >> 6;
    const int mw = wid >> 1, nw = wid & 1;
    const int lr = lane & 15, lk = lane >> 4;
    const int rowBase = blockIdx.y * 128;
    const int colBase = blockIdx.x * 128;
    const int g0 = colBase;

    STAGE_B(lsB[0], 0);
    STAGE_A(lsA[0], 0, 0);

    const int aswz = (lk ^ ((lr >> 1) & 3)) << 3;
    int aoff[4];
#pragma unroll
    for (int mf = 0; mf < 4; ++mf)
        aoff[mf] = (mw * 64 + mf * 16 + lr) * 32 + aswz;

    f32x4 acc[4][4] = {};
    for (int kx = 0; kx < NKX; ++kx) {
        const bool lastS = (kx == NKX - 1);
        if (!lastS) {
            STAGE_B(lsB[(kx + 1) % 3], kx + 1);
            STAGE_A(lsA[(kx + 1) % 3], 0, kx + 1);
        }
        if (lastS) { VMCNT(0); } else { VMCNT(4); }
        __builtin_amdgcn_s_barrier();
        asm volatile("" ::: "memory");
        const u16* la = lsA[kx % 3];
        const u16* lb = lsB[kx % 3];
        bf16x8 af[4], bfr[4];
#pragma unroll
        for (int mf = 0; mf < 4; ++mf)
            af[mf] = *(const bf16x8*)(la + aoff[mf]);
        const int rb = nw * 64 + lr;
        const int bswz = (lk ^ ((rb >> 1) & 3)) << 3;
#pragma unroll
        for (int nf = 0; nf < 4; ++nf)
            bfr[nf] = *(const bf16x8*)(lb + (rb + nf * 16) * 32 + bswz);
#pragma unroll
        for (int mf = 0; mf < 4; ++mf)
#pragma unroll
            for (int nf = 0; nf < 4; ++nf)
                acc[mf][nf] = __builtin_amdgcn_mfma_f32_16x16x32_bf16(
                    af[mf], bfr[nf], acc[mf][nf], 0, 0, 0);
    }

    u16* Zn = Z + (long)n * 1024 * 256;
#pragma unroll
    for (int mf = 0; mf < 4; ++mf) {
        const int co0 = rowBase + mw * 64 + mf * 16 + lk * 4;
#pragma unroll
        for (int nf = 0; nf < 4; ++nf) {
            const int col = colBase + nw * 64 + nf * 16 + lr;
            unsigned lo = (unsigned)f2bf(acc[mf][nf][0]) |
                          ((unsigned)f2bf(acc[mf][nf][1]) << 16);
            unsigned hi = (unsigned)f2bf(acc[mf][nf][2]) |
                          ((unsigned)f2bf(acc[mf][nf][3]) << 16);
            *(uint2*)(Zn + (long)col * 256 + co0) = make_uint2(lo, hi);
        }
    }
}

// ---------------- zw: one wave per low-res pixel, butterfly reduce ----------------
// zw[Q][j] = sum_co wl2T[co][j] * zbf[Q][co]
__global__ __launch_bounds__(256) void zw_kernel(
    const u16* __restrict__ zbfT, const float* __restrict__ wl2T,
    float* __restrict__ zwT)
{
    const int Q = (blockIdx.x * 256 + threadIdx.x) >> 6;   // 0..8191
    const int lane = threadIdx.x & 63;
    const int ci0 = lane * 4;
    uint2 v = *(const uint2*)(zbfT + (long)Q * 256 + ci0);
    float c[4] = { bf2f((u16)(v.x & 0xffff)), bf2f((u16)(v.x >> 16)),
                   bf2f((u16)(v.y & 0xffff)), bf2f((u16)(v.y >> 16)) };
    float s[8] = {};
#pragma unroll
    for (int t = 0; t < 4; ++t) {
        const float* wr = wl2T + (ci0 + t) * 8;
        float4 wa = *(const float4*)wr;
        float4 wb = *(const float4*)(wr + 4);
        s[0] += wa.x * c[t]; s[1] += wa.y * c[t]; s[2] += wa.z * c[t]; s[3] += wa.w * c[t];
        s[4] += wb.x * c[t]; s[5] += wb.y * c[t]; s[6] += wb.z * c[t]; s[7] += wb.w * c[t];
    }
#pragma unroll
    for (int off = 1; off < 64; off <<= 1)
#pragma unroll
        for (int j = 0; j < 8; ++j)
            s[j] += __shfl_xor(s[j], off, 64);
    if (lane == 0) {
        float* o = zwT + (long)Q * 8;
        *(float4*)o = make_float4(s[0], s[1], s[2], s[3]);
        *(float4*)(o + 4) = make_float4(s[4], s[5], s[6], s[7]);
    }
}

// ---------------- fuse_weights: v1=w_l1@i1 ; v2=CARAFE(zw)+c2 -> lw0 ----------------
__global__ __launch_bounds__(256) void fuse_weights_kernel(
    const float* __restrict__ input1, const float* __restrict__ zwT,
    const float* __restrict__ maskb, const float* __restrict__ bnp,  // 512.. c2
    const float* __restrict__ w_l1, const float* __restrict__ bn_l1,
    const float* __restrict__ bn_l2, const float* __restrict__ w_wl,
    const float* __restrict__ b_wl, float* __restrict__ lw0g)
{
    __shared__ float red[4][64][8];         // 8 KB
    __shared__ float zws[3 * 34 * 8];       // 3.2 KB : rows hq-1..hq+1, cols -1..32
    __shared__ float ml[32 * 36];           // 4.5 KB : mask row hq
    const int bx = blockIdx.x;              // 8 * 64
    const int n = bx >> 6;
    const int h = bx & 63;
    const int hq = h >> 1;
    const int p0 = h << 6;
    const int tid = threadIdx.x;

    for (int idx = tid; idx < 816; idx += 256) {
        int r = idx / 272, rem = idx - r * 272;
        int c = rem >> 3, j = rem & 7;
        int gr = hq - 1 + r, gc = c - 1;
        zws[(r * 34 + c) * 8 + j] =
            (gr >= 0 && gr < 32 && gc >= 0 && gc < 32)
                ? zwT[((long)n * 1024 + gr * 32 + gc) * 8 + j] : 0.f;
    }
    for (int idx = tid; idx < 1152; idx += 256)
        ml[idx] = maskb[((long)n * 1024 + hq * 32) * 36 + idx];

    const int pos = tid & 63;
    const int chunk = tid >> 6;
    const float* i1 = input1 + (long)n * 256 * 4096 + p0 + pos;
    {
        float s1[8] = {};
        for (int ci = chunk * 64; ci < chunk * 64 + 64; ++ci) {
            float x1 = i1[(long)ci * 4096];
#pragma unroll
            for (int j = 0; j < 8; ++j) s1[j] += w_l1[j * 256 + ci] * x1;
        }
#pragma unroll
        for (int j = 0; j < 8; ++j) red[chunk][pos][j] = s1[j];
    }
    __syncthreads();
    if (tid < 64) {
        float v[16];
#pragma unroll
        for (int j = 0; j < 8; ++j)
            v[j] = red[0][tid][j] + red[1][tid][j] + red[2][tid][j] + red[3][tid][j];
        const int wq = tid >> 1;
        const int q = ((h & 1) << 1) | (tid & 1);
        float m9[9];
#pragma unroll
        for (int k = 0; k < 9; ++k) m9[k] = ml[wq * 36 + k * 4 + q];
#pragma unroll
        for (int j = 0; j < 8; ++j) v[8 + j] = bnp[512 + j];
#pragma unroll
        for (int k = 0; k < 9; ++k) {
            int dh = k / 3 - 1, dw = k - (k / 3) * 3 - 1;
            const float* zp = zws + ((1 + dh) * 34 + wq + 1 + dw) * 8;
            float mk = m9[k];
#pragma unroll
            for (int j = 0; j < 8; ++j) v[8 + j] += mk * zp[j];
        }
        float z0 = b_wl[0], z1 = b_wl[1];
#pragma unroll
        for (int j = 0; j < 8; ++j) {
            float g = bn_l1[j], b = bn_l1[8 + j], m = bn_l1[16 + j], va = bn_l1[24 + j];
            float y = (v[j] - m) * (g * rsqrtf(va + EPS)) + b;
            float sv = y / (1.f + expf(-y));
            z0 += w_wl[j] * sv;
            z1 += w_wl[16 + j] * sv;
            g = bn_l2[j]; b = bn_l2[8 + j]; m = bn_l2[16 + j]; va = bn_l2[24 + j];
            y = (v[8 + j] - m) * (g * rsqrtf(va + EPS)) + b;
            sv = y / (1.f + expf(-y));
            z0 += w_wl[8 + j] * sv;
            z1 += w_wl[24 + j] * sv;
        }
        lw0g[(long)n * 4096 + p0 + tid] = 1.f / (1.f + expf(z1 - z0));
    }
}

// ---------------- border_zero: zero the 66x66 pad ring of fusedT ----------------
__global__ __launch_bounds__(256) void border_zero_kernel(u16* __restrict__ ftb)
{
    int gid = blockIdx.x * 256 + threadIdx.x;   // 8 * 260 * 32 uint4
    if (gid >= 8 * 260 * 32) return;
    int n = gid / (260 * 32);
    int rem = gid - n * (260 * 32);
    int r = rem >> 5;
    int i = rem & 31;
    int h, w;
    if (r < 66)       { h = 0;  w = r; }
    else if (r < 132) { h = 65; w = r - 66; }
    else { int j = r - 132; h = 1 + (j >> 1); w = (j & 1) * 65; }
    long prow = (long)h * 66 + w;
    uint4* dst = (uint4*)(ftb + (long)n * 4356 * 256 + prow * 256) + i;
    *dst = make_uint4(0, 0, 0, 0);
}

// ---------------- carafe_blend: u=CARAFE(z)+b_up ; blend ; transposed write ----------------
__global__ __launch_bounds__(256) void carafe_blend_kernel(
    const float* __restrict__ i1g, const u16* __restrict__ zbfT,
    const float* __restrict__ maskb, const float* __restrict__ lw0g,
    const float* __restrict__ bnp,          // 768.. b_up
    u16* __restrict__ dst)
{
    __shared__ __align__(16) u16 zbf[54 * 264];     // 27.8 KB
    __shared__ float mlds[16 * 36];                 // 2.3 KB
    __shared__ float lw0s[32];
    __shared__ __align__(16) u16 lds2[32 * 264];    // 16.5 KB
    const int n = blockIdx.y;
    const int h = blockIdx.x >> 1;
    const int w0 = (blockIdx.x & 1) << 5;
    const int hq = h >> 1;
    const int wq0 = w0 >> 1;
    const int tid = threadIdx.x;

    for (int idx = tid; idx < 54 * 32; idx += 256) {
        int px = idx >> 5, unit = idx & 31;
        int r = px / 18, c = px - r * 18;
        int gr = hq - 1 + r, gc = wq0 - 1 + c;
        uint4 v = make_uint4(0u, 0u, 0u, 0u);
        if (gr >= 0 && gr < 32 && gc >= 0 && gc < 32)
            v = *(const uint4*)(zbfT + ((long)n * 1024 + gr * 32 + gc) * 256 + unit * 8);
        *(uint4*)(zbf + px * 264 + unit * 8) = v;
    }
    for (int idx = tid; idx < 576; idx += 256)
        mlds[idx] = maskb[((long)n * 1024 + hq * 32 + wq0) * 36 + idx];
    if (tid < 32)
        lw0s[tid] = lw0g[(long)n * 4096 + (h << 6) + w0 + tid];
    __syncthreads();

    const int w = tid & 31;
    const int chunk = tid >> 5;
    const float* i1 = i1g + (long)n * 256 * 4096 + (h << 6) + w0 + w;
    {
        const float lw = lw0s[w], lw1 = 1.f - lw;
        const int wp = w0 + w;
        const int wqm = (wp >> 1) - wq0;
        const int q = ((h & 1) << 1) | (wp & 1);
        float m9[9];
#pragma unroll
        for (int k = 0; k < 9; ++k) m9[k] = mlds[wqm * 36 + k * 4 + q];
        for (int ci = chunk * 32; ci < chunk * 32 + 32; ci += 8) {
            float uu[8];
            {
                float4 ba = *(const float4*)(bnp + 768 + ci);
                float4 bb = *(const float4*)(bnp + 768 + ci + 4);
                uu[0] = ba.x; uu[1] = ba.y; uu[2] = ba.z; uu[3] = ba.w;
                uu[4] = bb.x; uu[5] = bb.y; uu[6] = bb.z; uu[7] = bb.w;
            }
#pragma unroll
            for (int k = 0; k < 9; ++k) {
                int dh = k / 3 - 1, dw = k - (k / 3) * 3 - 1;
                uint4 vz = *(const uint4*)(zbf + ((1 + dh) * 18 + wqm + 1 + dw) * 264 + ci);
                float mk = m9[k];
                uu[0] += mk * bf2f((u16)(vz.x & 0xffff));
                uu[1] += mk * bf2f((u16)(vz.x >> 16));
                uu[2] += mk * bf2f((u16)(vz.y & 0xffff));
                uu[3] += mk * bf2f((u16)(vz.y >> 16));
                uu[4] += mk * bf2f((u16)(vz.z & 0xffff));
                uu[5] += mk * bf2f((u16)(vz.z >> 16));
                uu[6] += mk * bf2f((u16)(vz.w & 0xffff));
                uu[7] += mk * bf2f((u16)(vz.w >> 16));
            }
            unsigned o0 = (unsigned)f2bf(i1[(long)ci * 4096] * lw + uu[0] * lw1)
                        | ((unsigned)f2bf(i1[(long)(ci + 1) * 4096] * lw + uu[1] * lw1) << 16);
            unsigned o1 = (unsigned)f2bf(i1[(long)(ci + 2) * 4096] * lw + uu[2] * lw1)
                        | ((unsigned)f2bf(i1[(long)(ci + 3) * 4096] * lw + uu[3] * lw1) << 16);
            unsigned o2 = (unsigned)f2bf(i1[(long)(ci + 4) * 4096] * lw + uu[4] * lw1)
                        | ((unsigned)f2bf(i1[(long)(ci + 5) * 4096] * lw + uu[5] * lw1) << 16);
            unsigned o3 = (unsigned)f2bf(i1[(long)(ci + 6) * 4096] * lw + uu[6] * lw1)
                        | ((unsigned)f2bf(i1[(long)(ci + 7) * 4096] * lw + uu[7] * lw1) << 16);
            *(uint4*)(lds2 + w * 264 + ci) = make_uint4(o0, o1, o2, o3);
        }
    }
    __syncthreads();
    {
        const int px = tid >> 3, qd = tid & 7;
        const int pg = (h << 6) + w0 + px;
        long prow = (long)((pg >> 6) + 1) * 66 + (pg & 63) + 1;
        u16* drow = dst + (long)n * 4356 * 256 + prow * 256;
        const u16* lrow = lds2 + px * 264;
#pragma unroll
        for (int j = 0; j < 16; ++j) {
            int off = j * 16 + qd * 2;
            *(unsigned*)(drow + off) = *(const unsigned*)(lrow + off);
        }
    }
}

// ---------------- K7: m97+T4 GEMM — triple-buf LDS, counted vmcnt ----------------
template<int KCC, int NT, bool PADDED>
__global__ __launch_bounds__(256, 2) void gemm_m97_kernel(
    const u16* __restrict__ A,      // [NT][256][KCC] bf16
    const u16* __restrict__ B,      // per image [rows][KCC] bf16
    const float* __restrict__ scale, const float* __restrict__ shift,
    float* __restrict__ C, long strideB, long strideC, int silu)
{
    constexpr int RROWS = PADDED ? 264 : 128;
    constexpr int BUNITS = RROWS * 4;
    constexpr int NKX = KCC / 32;
    constexpr int MINB = BUNITS / 256;
    __shared__ __align__(16) u16 lsA[3][128 * 32];
    __shared__ __align__(16) u16 lsB[3][RROWS * 32];
    const int n = blockIdx.z;
    const u16* Bn = B + (long)n * strideB;
    float* Cn = C + (long)n * strideC;
    const int tid = threadIdx.x;
    const int lane = tid & 63;
    const int wid = tid >> 6;
    const int mw = wid >> 1, nw = wid & 1;
    const int lr = lane & 15, lk = lane >> 4;
    const int rowBase = blockIdx.y * 128;
    const int colBase = blockIdx.x * 128;
    const int g0 = PADDED ? (colBase >> 6) * 66 : colBase;

    STAGE_B(lsB[0], 0);
    STAGE_A(lsA[0], 0, 0);

    const int aswz = (lk ^ ((lr >> 1) & 3)) << 3;
    int aoff[4];
#pragma unroll
    for (int mf = 0; mf < 4; ++mf)
        aoff[mf] = (mw * 64 + mf * 16 + lr) * 32 + aswz;

    f32x4 acc[4][4] = {};
    for (int kx = 0; kx < NKX; ++kx) {
        const u16* lb = lsB[kx % 3];
#pragma unroll
        for (int t = 0; t < NT; ++t) {
            const int s = kx * NT + t;
            const bool lastS = (kx == NKX - 1) && (t == NT - 1);
            const bool stgB = (t == 0) && (kx + 1 < NKX);
            if (stgB) STAGE_B(lsB[(kx + 1) % 3], kx + 1);
            if (!lastS) {
                const int t1 = (t + 1 == NT) ? 0 : t + 1;
                const int kx1 = (t + 1 == NT) ? kx + 1 : kx;
                STAGE_A(lsA[(s + 1) % 3], t1, kx1);
            }
            if (lastS) { VMCNT(0); }
            else if (stgB) { if constexpr (MINB == 2) VMCNT(4); else VMCNT(6); }
            else { VMCNT(2); }
            __builtin_amdgcn_s_barrier();
            asm volatile("" ::: "memory");

            const u16* la = lsA[s % 3];
            bf16x8 af[4], bfr[4];
#pragma unroll
            for (int mf = 0; mf < 4; ++mf)
                af[mf] = *(const bf16x8*)(la + aoff[mf]);
            int rb;
            if (PADDED) {
                int dh = t / 3 - 1, dw = t - (t / 3) * 3 - 1;
                rb = (nw + dh + 1) * 66 + dw + 1 + lr;
            } else {
                rb = nw * 64 + lr;
            }
            const int bswz = (lk ^ ((rb >> 1) & 3)) << 3;
#pragma unroll
            for (int nf = 0; nf < 4; ++nf)
                bfr[nf] = *(const bf16x8*)(lb + (rb + nf * 16) * 32 + bswz);
#pragma unroll
            for (int mf = 0; mf < 4; ++mf)
#pragma unroll
                for (int nf = 0; nf < 4; ++nf)
                    acc[mf][nf] = __builtin_amdgcn_mfma_f32_16x16x32_bf16(
                        af[mf], bfr[nf], acc[mf][nf], 0, 0, 0);
        }
    }

#pragma unroll
    for (int mf = 0; mf < 4; ++mf) {
#pragma unroll
        for (int reg = 0; reg < 4; ++reg) {
            int co = rowBase + mw * 64 + mf * 16 + lk * 4 + reg;
            float sc = scale[co], sh = shift[co];
#pragma unroll
            for (int nf = 0; nf < 4; ++nf) {
                int col = colBase + nw * 64 + nf * 16 + lr;
                float y = acc[mf][nf][reg] * sc + sh;
                if (silu) y = y / (1.f + expf(-y));
                Cn[(long)co * 4096 + col] = y;
            }
        }
    }
}

// ---------------- prep kernels ----------------
__global__ __launch_bounds__(256) void prep_w_kernel(
    const float* __restrict__ w_conv, const float* __restrict__ w_up,
    const float* __restrict__ w_enc,
    u16* __restrict__ wT, u16* __restrict__ wupT, u16* __restrict__ wencT)
{
    int gid = blockIdx.x * 256 + threadIdx.x;
    if (gid < 589824) {             // wT[t][co][ci] = w_conv[co][ci][t]
        int t = gid >> 16;
        int co = (gid >> 8) & 255;
        int ci = gid & 255;
        wT[gid] = f2bf(w_conv[(co * 256 + ci) * 9 + t]);
    }
    if (gid < 131072) wupT[gid] = f2bf(w_up[gid]);
    if (gid < 73728) {              // wencT[t][co<64][ci] (zeros co>=36)
        int t = gid >> 13;
        int co = (gid >> 7) & 63;
        int ci = gid & 127;
        wencT[gid] = (co < 36) ? f2bf(w_enc[(co * 128 + ci) * 9 + t]) : (u16)0;
    }
}

__global__ void prep_bn_kernel(const float* __restrict__ bn_conv,
                               const float* __restrict__ b_up,
                               const float* __restrict__ w_l2,
                               float* __restrict__ bnp, float* __restrict__ wl2T)
{
    int i = threadIdx.x;            // 256
    float g = bn_conv[i], b = bn_conv[256 + i], m = bn_conv[512 + i], v = bn_conv[768 + i];
    float sc = g * rsqrtf(v + EPS);
    bnp[i] = sc;
    bnp[256 + i] = b - m * sc;
    bnp[768 + i] = b_up[i];
    if (i < 8) {                    // c2[j] = w_l2[j] . b_up
        float s = 0.f;
        for (int co = 0; co < 256; ++co) s += w_l2[i * 256 + co] * b_up[co];
        bnp[512 + i] = s;
    }
#pragma unroll
    for (int j = 0; j < 8; ++j)     // wl2T[co][j]
        wl2T[i * 8 + j] = w_l2[j * 256 + i];
}

extern "C" void kernel_launch(void* const* d_in, const int* in_sizes, int n_in,
                              void* d_out, int out_size, void* d_ws, size_t ws_size,
                              hipStream_t stream)
{
    const float* input1 = (const float*)d_in[0];
    const float* input2 = (const float*)d_in[1];
    const float* w_down = (const float*)d_in[2];
    const float* b_down = (const float*)d_in[3];
    const float* w_enc  = (const float*)d_in[4];
    const float* b_enc  = (const float*)d_in[5];
    const float* w_up   = (const float*)d_in[6];
    const float* b_up   = (const float*)d_in[7];
    const float* w_l1   = (const float*)d_in[8];
    const float* bn_l1  = (const float*)d_in[9];
    const float* w_l2   = (const float*)d_in[10];
    const float* bn_l2  = (const float*)d_in[11];
    const float* w_wl   = (const float*)d_in[12];
    const float* b_wl   = (const float*)d_in[13];
    const float* w_conv = (const float*)d_in[14];
    const float* bn_conv= (const float*)d_in[15];
    float* out = (float*)d_out;

    // workspace layout (float units). ~38 MB total.
    float* ws     = (float*)d_ws;
    float* ktTf   = ws;                      //   591,872 f : ktT bf16 [n][1156][128]
    float* wencTf = ktTf + 591872;           //    36,864 f
    float* kt2    = wencTf + 36864;          //   294,912 f
    float* maskb  = kt2 + 294912;            //   294,912 f
    float* in2Tf  = maskb + 294912;          // 2,097,152 f : in2T bf16 [n][1024][512]
    float* zbfTf  = in2Tf + 2097152;         // 1,048,576 f : zbfT bf16 [n][1024][256]
    float* zwT    = zbfTf + 1048576;         //    65,536 f : [n][1024][8] fp32
    float* lw0g   = zwT + 65536;             //    32,768 f : [n][4096]
    float* ftbf   = lw0g + 32768;            // 4,460,544 f : fusedT bf16 [n][4356][256]
    float* wTf    = ftbf + 4460544;          //   294,912 f
    float* wupTf  = wTf + 294912;            //    65,536 f
    float* wl2T   = wupTf + 65536;           //     2,048 f
    float* bnp    = wl2T + 2048;             //     1,024 f
    u16* ktT      = (u16*)ktTf;
    u16* wencT    = (u16*)wencTf;
    u16* in2T     = (u16*)in2Tf;
    u16* zbfT     = (u16*)zbfTf;
    u16* ftb      = (u16*)ftbf;
    u16* wT       = (u16*)wTf;
    u16* wupT     = (u16*)wupTf;

    // prep (independent)
    prep_w_kernel<<<dim3(2304), 256, 0, stream>>>(w_conv, w_up, w_enc, wT, wupT, wencT);
    prep_bn_kernel<<<dim3(1), 256, 0, stream>>>(bn_conv, b_up, w_l2, bnp, wl2T);
    border_zero_kernel<<<dim3(260), 256, 0, stream>>>(ftb);

    // mask pipeline
    hipMemsetAsync(ktT, 0, 8L * 1156 * 128 * 2, stream);
    down_gemm_kernel<<<dim3(16, 2, 8), 256, 0, stream>>>(w_down, input2, b_down, ktT);
    enc_mfma_kernel<<<dim3(64, 8), 64, 0, stream>>>(wencT, ktT, b_enc, kt2);
    mask_softmax_kernel<<<dim3(128), 256, 0, stream>>>(kt2, maskb);

    // z pipeline (commuted up-conv at low res)
    in2t_kernel<<<dim3(32, 8), 256, 0, stream>>>(input2, in2T);
    zgemm_kernel<<<dim3(8, 2, 8), 256, 0, stream>>>(wupT, in2T, zbfT);
    zw_kernel<<<dim3(2048), 256, 0, stream>>>(zbfT, wl2T, zwT);

    // level weights -> lw0 (reads i1 once)
    fuse_weights_kernel<<<dim3(512), 256, 0, stream>>>(
        input1, zwT, maskb, bnp, w_l1, bn_l1, bn_l2, w_wl, b_wl, lw0g);

    // CARAFE + blend -> fusedT
    carafe_blend_kernel<<<dim3(128, 8), 256, 0, stream>>>(
        input1, zbfT, maskb, lw0g, bnp, ftb);

    // K7: final conv (m97+T4, 9-tap) + BN + SiLU
    gemm_m97_kernel<256, 9, true><<<dim3(32, 2, 8), 256, 0, stream>>>(
        wT, ftb, bnp, bnp + 256, out, 4356L * 256, 256L * 4096, 1);
}

// Round 15
// 171.652 us; speedup vs baseline: 1.5126x; 1.0982x over previous
//
#include <hip/hip_runtime.h>
#include <math.h>

// ASFF_2: N=8, C1=256, C2=512, H=64, W=64, low-res 32x32.
// CARAFE-commutation: u = CARAFE(z)+b_up with z = w_up@in2 (low-res GEMM);
// v2 = CARAFE(zw)+c2 with zw = w_l2@z, c2 = w_l2@b_up.
//  in2t: input2 -> in2T bf16 [n][1024][512]
//  down_mfma: ktT = bf16T(w_down @ in2T + b_down) [n][34*34][128] padded
//  enc_mfma -> kt2 ; softmax -> maskb
//  zgemm: zbfT = bf16(w_up @ in2T) [n][1024][256]
//  zw: zwT[n][1024][8] = w_l2 @ z
//  fuse_weights: v1 = w_l1@i1, v2 = CARAFE(zw)+c2 -> lw0[n][4096]
//  carafe_blend: u=CARAFE(z)+b_up, blend with i1 -> fusedT bf16 [66x66][256]
//  K7: m97 GEMM, post-barrier 2-phase-deep staging, uniform counted vmcnt.
// Pipeline discipline: all global_load_lds issued AFTER s_barrier (no
// pre-barrier laggard can read the target buffer => A triple-buffer at
// 2-phase lead is WAR-safe); VMCNT leaves only the newest phase's issues.

#define EPS 1e-5f
typedef unsigned short u16;
typedef __attribute__((ext_vector_type(8))) __bf16 bf16x8;
typedef __attribute__((ext_vector_type(4))) float f32x4;

#define VMCNT(N) asm volatile("s_waitcnt vmcnt(" #N ")" ::: "memory")

__device__ inline u16 f2bf(float x) {
    union { float f; unsigned u; } v; v.f = x;
    unsigned r = v.u + 0x7FFF + ((v.u >> 16) & 1);
    return (u16)(r >> 16);
}
__device__ inline float bf2f(u16 x) {
    union { unsigned u; float f; } v; v.u = (unsigned)x << 16; return v.f;
}

// ---------------- in2t: transpose-cast input2 [512][1024] -> in2T bf16 [q][512] ----------------
__global__ __launch_bounds__(256) void in2t_kernel(
    const float* __restrict__ src0, u16* __restrict__ dst)
{
    __shared__ u16 lds[32 * 514];
    const int n = blockIdx.y;
    const int p0 = blockIdx.x * 32;
    const int tid = threadIdx.x;
    {
        const int w = tid & 31;
        const int chunk = tid >> 5;
        const float* src = src0 + (long)n * 512 * 1024 + p0 + w;
        for (int ci = chunk * 64; ci < chunk * 64 + 64; ++ci)
            lds[w * 514 + ci] = f2bf(src[(long)ci * 1024]);
    }
    __syncthreads();
    const int px = tid >> 3;
    const int qd = tid & 7;
    u16* drow = dst + ((long)n * 1024 + p0 + px) * 512;
    const u16* lrow = lds + px * 514;
#pragma unroll
    for (int j = 0; j < 32; ++j) {
        int off = j * 16 + qd * 2;
        *(unsigned*)(drow + off) = *(const unsigned*)(lrow + off);
    }
}

// ---------------- staging macros ----------------
#define STAGE_A(dstp, t, kx)                                                         \
    {                                                                                \
        const u16* Abase = A + ((long)(t) * 256 + rowBase) * KCC + (kx) * 32;        \
        _Pragma("unroll")                                                            \
        for (int ii = 0; ii < 2; ++ii) {                                             \
            int f = ii * 256 + tid;                                                  \
            int r = f >> 2, uu = f & 3;                                              \
            __builtin_amdgcn_global_load_lds(                                        \
                (const __attribute__((address_space(1))) void*)                      \
                    (Abase + (long)r * KCC + ((uu ^ ((r >> 1) & 3)) << 3)),          \
                (__attribute__((address_space(3))) void*)((dstp) + f * 8),           \
                16, 0, 0);                                                           \
        }                                                                            \
    }

#define STAGE_B(dstp, kx)                                                            \
    {                                                                                \
        const u16* Bbase = Bn + (long)g0 * KCC + (kx) * 32;                          \
        for (int f = tid; f < BUNITS; f += 256) {                                    \
            int r = f >> 2, uu = f & 3;                                              \
            __builtin_amdgcn_global_load_lds(                                        \
                (const __attribute__((address_space(1))) void*)                      \
                    (Bbase + (long)r * KCC + ((uu ^ ((r >> 1) & 3)) << 3)),          \
                (__attribute__((address_space(3))) void*)((dstp) + f * 8),           \
                16, 0, 0);                                                           \
        }                                                                            \
    }

// ---------------- lowres GEMM core (zgemm / down_mfma): KCC=512, 16 phases ----------------
// Post-barrier staging, 2-phase lead, A/B triple-buffered, VMCNT(4).
#define LOWRES_GEMM_BODY(MROWS)                                                      \
    constexpr int KCC = 512;                                                         \
    constexpr int BUNITS = 512;                                                      \
    __shared__ __align__(16) u16 lsA[3][128 * 32];                                   \
    __shared__ __align__(16) u16 lsB[3][128 * 32];                                   \
    const int n = blockIdx.z;                                                        \
    const u16* Bn = B + (long)n * 1024 * 512;                                        \
    const int tid = threadIdx.x;                                                     \
    const int lane = tid & 63;                                                       \
    const int wid = tid >> 6;                                                        \
    const int mw = wid >> 1, nw = wid & 1;                                           \
    const int lr = lane & 15, lk = lane >> 4;                                        \
    const int rowBase = blockIdx.y * 128;                                            \
    const int colBase = blockIdx.x * 128;                                            \
    const int g0 = colBase;                                                          \
    STAGE_A(lsA[0], 0, 0); STAGE_B(lsB[0], 0);                                       \
    STAGE_A(lsA[1], 0, 1); STAGE_B(lsB[1], 1);                                       \
    const int aswz = (lk ^ ((lr >> 1) & 3)) << 3;                                    \
    int aoff[4];                                                                     \
    _Pragma("unroll")                                                                \
    for (int mf = 0; mf < 4; ++mf)                                                   \
        aoff[mf] = (mw * 64 + mf * 16 + lr) * 32 + aswz;                             \
    f32x4 acc[4][4] = {};                                                            \
    for (int kx = 0; kx < 16; ++kx) {                                                \
        if (kx == 15) { VMCNT(0); } else { VMCNT(4); }                               \
        __builtin_amdgcn_s_barrier();                                                \
        asm volatile("" ::: "memory");                                               \
        if (kx + 2 < 16) {                                                           \
            STAGE_A(lsA[(kx + 2) % 3], 0, kx + 2);                                   \
            STAGE_B(lsB[(kx + 2) % 3], kx + 2);                                      \
        }                                                                            \
        const u16* la = lsA[kx % 3];                                                 \
        const u16* lb = lsB[kx % 3];                                                 \
        bf16x8 af[4], bfr[4];                                                        \
        _Pragma("unroll")                                                            \
        for (int mf = 0; mf < 4; ++mf)                                               \
            af[mf] = *(const bf16x8*)(la + aoff[mf]);                                \
        const int rb = nw * 64 + lr;                                                 \
        const int bswz = (lk ^ ((rb >> 1) & 3)) << 3;                                \
        _Pragma("unroll")                                                            \
        for (int nf = 0; nf < 4; ++nf)                                               \
            bfr[nf] = *(const bf16x8*)(lb + (rb + nf * 16) * 32 + bswz);             \
        _Pragma("unroll")                                                            \
        for (int mf = 0; mf < 4; ++mf)                                               \
            _Pragma("unroll")                                                        \
            for (int nf = 0; nf < 4; ++nf)                                           \
                acc[mf][nf] = __builtin_amdgcn_mfma_f32_16x16x32_bf16(               \
                    af[mf], bfr[nf], acc[mf][nf], 0, 0, 0);                          \
    }

// ---------------- zgemm: zbfT = bf16(w_up @ in2T)  [n][1024][256] ----------------
__global__ __launch_bounds__(256, 2) void zgemm_kernel(
    const u16* __restrict__ A,      // wupT [256][512]
    const u16* __restrict__ B,      // in2T [n][1024][512]
    u16* __restrict__ Z)            // zbfT [n][1024][256]
{
    LOWRES_GEMM_BODY(256)
    u16* Zn = Z + (long)n * 1024 * 256;
#pragma unroll
    for (int mf = 0; mf < 4; ++mf) {
        const int co0 = rowBase + mw * 64 + mf * 16 + lk * 4;
#pragma unroll
        for (int nf = 0; nf < 4; ++nf) {
            const int col = colBase + nw * 64 + nf * 16 + lr;
            unsigned lo = (unsigned)f2bf(acc[mf][nf][0]) |
                          ((unsigned)f2bf(acc[mf][nf][1]) << 16);
            unsigned hi = (unsigned)f2bf(acc[mf][nf][2]) |
                          ((unsigned)f2bf(acc[mf][nf][3]) << 16);
            *(uint2*)(Zn + (long)col * 256 + co0) = make_uint2(lo, hi);
        }
    }
}

// ---------------- down_mfma: ktT = bf16T(w_down @ in2T + b_down), padded 34x34 ----------------
__global__ __launch_bounds__(256, 2) void down_mfma_kernel(
    const u16* __restrict__ A,      // wdT [128][512]
    const u16* __restrict__ B,      // in2T [n][1024][512]
    const float* __restrict__ bias, u16* __restrict__ ktT)
{
    LOWRES_GEMM_BODY(128)
    u16* Kn = ktT + (long)n * 1156 * 128;
#pragma unroll
    for (int mf = 0; mf < 4; ++mf) {
        const int co0 = mw * 64 + mf * 16 + lk * 4;     // 0..124
        float b0 = bias[co0], b1 = bias[co0 + 1], b2 = bias[co0 + 2], b3 = bias[co0 + 3];
#pragma unroll
        for (int nf = 0; nf < 4; ++nf) {
            const int col = colBase + nw * 64 + nf * 16 + lr;   // 0..1023
            const int pr = ((col >> 5) + 1) * 34 + (col & 31) + 1;
            unsigned lo = (unsigned)f2bf(acc[mf][nf][0] + b0) |
                          ((unsigned)f2bf(acc[mf][nf][1] + b1) << 16);
            unsigned hi = (unsigned)f2bf(acc[mf][nf][2] + b2) |
                          ((unsigned)f2bf(acc[mf][nf][3] + b3) << 16);
            *(uint2*)(Kn + (long)pr * 128 + co0) = make_uint2(lo, hi);
        }
    }
}

// ---------------- enc_mfma: encoder conv as 9-tap shifted MFMA GEMM ----------------
__global__ __launch_bounds__(64) void enc_mfma_kernel(
    const u16* __restrict__ A, const u16* __restrict__ B,
    const float* __restrict__ bias, float* __restrict__ C)
{
    const int n = blockIdx.y;
    const int lane = threadIdx.x;
    const int lr = lane & 15, lk = lane >> 4;
    const int p = blockIdx.x * 16 + lr;
    const int pr = ((p >> 5) + 1) * 34 + (p & 31) + 1;
    const u16* Bn = B + (long)n * 1156 * 128;
    const int bOff = pr * 128 + lk * 8;
    f32x4 acc[3] = {};
    for (int t = 0; t < 9; ++t) {
        const u16* At = A + t * 8192;
        const int btap = ((t / 3 - 1) * 34 + (t % 3 - 1)) * 128;
#pragma unroll
        for (int k0 = 0; k0 < 128; k0 += 32) {
            bf16x8 bf = *(const bf16x8*)(Bn + bOff + btap + k0);
#pragma unroll
            for (int mf = 0; mf < 3; ++mf) {
                bf16x8 af = *(const bf16x8*)(At + (mf * 16 + lr) * 128 + lk * 8 + k0);
                acc[mf] = __builtin_amdgcn_mfma_f32_16x16x32_bf16(af, bf, acc[mf], 0, 0, 0);
            }
        }
    }
    float* Cn = C + (long)n * 36 * 1024;
#pragma unroll
    for (int mf = 0; mf < 3; ++mf)
#pragma unroll
        for (int reg = 0; reg < 4; ++reg) {
            int co = mf * 16 + lk * 4 + reg;
            if (co < 36)
                Cn[(long)co * 1024 + p] = acc[mf][reg] + bias[co];
        }
}

// ---------------- softmax over k=9 ----------------
__global__ __launch_bounds__(256) void mask_softmax_kernel(
    const float* __restrict__ kt2, float* __restrict__ mask)
{
    int gid = blockIdx.x * 256 + threadIdx.x;   // N*1024*4
    int q = gid & 3;
    int p = (gid >> 2) & 1023;
    int n = gid >> 12;
    float s[9];
    float mx = -1e30f;
#pragma unroll
    for (int k = 0; k < 9; ++k) {
        s[k] = kt2[(long)(n * 36 + k * 4 + q) * 1024 + p];
        mx = fmaxf(mx, s[k]);
    }
    float sum = 0.f;
#pragma unroll
    for (int k = 0; k < 9; ++k) { s[k] = expf(s[k] - mx); sum += s[k]; }
    float inv = 1.f / sum;
    float* mp = mask + (long)(n * 1024 + p) * 36 + q;
#pragma unroll
    for (int k = 0; k < 9; ++k) mp[k * 4] = s[k] * inv;
}

// ---------------- zw: one wave per low-res pixel, butterfly reduce ----------------
__global__ __launch_bounds__(256) void zw_kernel(
    const u16* __restrict__ zbfT, const float* __restrict__ wl2T,
    float* __restrict__ zwT)
{
    const int Q = (blockIdx.x * 256 + threadIdx.x) >> 6;   // 0..8191
    const int lane = threadIdx.x & 63;
    const int ci0 = lane * 4;
    uint2 v = *(const uint2*)(zbfT + (long)Q * 256 + ci0);
    float c[4] = { bf2f((u16)(v.x & 0xffff)), bf2f((u16)(v.x >> 16)),
                   bf2f((u16)(v.y & 0xffff)), bf2f((u16)(v.y >> 16)) };
    float s[8] = {};
#pragma unroll
    for (int t = 0; t < 4; ++t) {
        const float* wr = wl2T + (ci0 + t) * 8;
        float4 wa = *(const float4*)wr;
        float4 wb = *(const float4*)(wr + 4);
        s[0] += wa.x * c[t]; s[1] += wa.y * c[t]; s[2] += wa.z * c[t]; s[3] += wa.w * c[t];
        s[4] += wb.x * c[t]; s[5] += wb.y * c[t]; s[6] += wb.z * c[t]; s[7] += wb.w * c[t];
    }
#pragma unroll
    for (int off = 1; off < 64; off <<= 1)
#pragma unroll
        for (int j = 0; j < 8; ++j)
            s[j] += __shfl_xor(s[j], off, 64);
    if (lane == 0) {
        float* o = zwT + (long)Q * 8;
        *(float4*)o = make_float4(s[0], s[1], s[2], s[3]);
        *(float4*)(o + 4) = make_float4(s[4], s[5], s[6], s[7]);
    }
}

// ---------------- fuse_weights: v1=w_l1@i1 ; v2=CARAFE(zw)+c2 -> lw0 ----------------
__global__ __launch_bounds__(256) void fuse_weights_kernel(
    const float* __restrict__ input1, const float* __restrict__ zwT,
    const float* __restrict__ maskb, const float* __restrict__ bnp,  // 512.. c2
    const float* __restrict__ w_l1, const float* __restrict__ bn_l1,
    const float* __restrict__ bn_l2, const float* __restrict__ w_wl,
    const float* __restrict__ b_wl, float* __restrict__ lw0g)
{
    __shared__ float red[4][64][8];
    __shared__ float zws[3 * 34 * 8];
    __shared__ float ml[32 * 36];
    const int bx = blockIdx.x;              // 8 * 64
    const int n = bx >> 6;
    const int h = bx & 63;
    const int hq = h >> 1;
    const int p0 = h << 6;
    const int tid = threadIdx.x;

    for (int idx = tid; idx < 816; idx += 256) {
        int r = idx / 272, rem = idx - r * 272;
        int c = rem >> 3, j = rem & 7;
        int gr = hq - 1 + r, gc = c - 1;
        zws[(r * 34 + c) * 8 + j] =
            (gr >= 0 && gr < 32 && gc >= 0 && gc < 32)
                ? zwT[((long)n * 1024 + gr * 32 + gc) * 8 + j] : 0.f;
    }
    for (int idx = tid; idx < 1152; idx += 256)
        ml[idx] = maskb[((long)n * 1024 + hq * 32) * 36 + idx];

    const int pos = tid & 63;
    const int chunk = tid >> 6;
    const float* i1 = input1 + (long)n * 256 * 4096 + p0 + pos;
    {
        float s1[8] = {};
        for (int ci = chunk * 64; ci < chunk * 64 + 64; ++ci) {
            float x1 = i1[(long)ci * 4096];
#pragma unroll
            for (int j = 0; j < 8; ++j) s1[j] += w_l1[j * 256 + ci] * x1;
        }
#pragma unroll
        for (int j = 0; j < 8; ++j) red[chunk][pos][j] = s1[j];
    }
    __syncthreads();
    if (tid < 64) {
        float v[16];
#pragma unroll
        for (int j = 0; j < 8; ++j)
            v[j] = red[0][tid][j] + red[1][tid][j] + red[2][tid][j] + red[3][tid][j];
        const int wq = tid >> 1;
        const int q = ((h & 1) << 1) | (tid & 1);
        float m9[9];
#pragma unroll
        for (int k = 0; k < 9; ++k) m9[k] = ml[wq * 36 + k * 4 + q];
#pragma unroll
        for (int j = 0; j < 8; ++j) v[8 + j] = bnp[512 + j];
#pragma unroll
        for (int k = 0; k < 9; ++k) {
            int dh = k / 3 - 1, dw = k - (k / 3) * 3 - 1;
            const float* zp = zws + ((1 + dh) * 34 + wq + 1 + dw) * 8;
            float mk = m9[k];
#pragma unroll
            for (int j = 0; j < 8; ++j) v[8 + j] += mk * zp[j];
        }
        float z0 = b_wl[0], z1 = b_wl[1];
#pragma unroll
        for (int j = 0; j < 8; ++j) {
            float g = bn_l1[j], b = bn_l1[8 + j], m = bn_l1[16 + j], va = bn_l1[24 + j];
            float y = (v[j] - m) * (g * rsqrtf(va + EPS)) + b;
            float sv = y / (1.f + expf(-y));
            z0 += w_wl[j] * sv;
            z1 += w_wl[16 + j] * sv;
            g = bn_l2[j]; b = bn_l2[8 + j]; m = bn_l2[16 + j]; va = bn_l2[24 + j];
            y = (v[8 + j] - m) * (g * rsqrtf(va + EPS)) + b;
            sv = y / (1.f + expf(-y));
            z0 += w_wl[8 + j] * sv;
            z1 += w_wl[24 + j] * sv;
        }
        lw0g[(long)n * 4096 + p0 + tid] = 1.f / (1.f + expf(z1 - z0));
    }
}

// ---------------- border_zero ----------------
__global__ __launch_bounds__(256) void border_zero_kernel(u16* __restrict__ ftb)
{
    int gid = blockIdx.x * 256 + threadIdx.x;   // 8 * 260 * 32 uint4
    if (gid >= 8 * 260 * 32) return;
    int n = gid / (260 * 32);
    int rem = gid - n * (260 * 32);
    int r = rem >> 5;
    int i = rem & 31;
    int h, w;
    if (r < 66)       { h = 0;  w = r; }
    else if (r < 132) { h = 65; w = r - 66; }
    else { int j = r - 132; h = 1 + (j >> 1); w = (j & 1) * 65; }
    long prow = (long)h * 66 + w;
    uint4* dst = (uint4*)(ftb + (long)n * 4356 * 256 + prow * 256) + i;
    *dst = make_uint4(0, 0, 0, 0);
}

// ---------------- carafe_blend: u=CARAFE(z)+b_up ; blend ; transposed write ----------------
__global__ __launch_bounds__(256) void carafe_blend_kernel(
    const float* __restrict__ i1g, const u16* __restrict__ zbfT,
    const float* __restrict__ maskb, const float* __restrict__ lw0g,
    const float* __restrict__ bnp,          // 768.. b_up
    u16* __restrict__ dst)
{
    __shared__ __align__(16) u16 zbf[54 * 264];
    __shared__ float mlds[16 * 36];
    __shared__ float lw0s[32];
    __shared__ __align__(16) u16 lds2[32 * 264];
    const int n = blockIdx.y;
    const int h = blockIdx.x >> 1;
    const int w0 = (blockIdx.x & 1) << 5;
    const int hq = h >> 1;
    const int wq0 = w0 >> 1;
    const int tid = threadIdx.x;

    for (int idx = tid; idx < 54 * 32; idx += 256) {
        int px = idx >> 5, unit = idx & 31;
        int r = px / 18, c = px - r * 18;
        int gr = hq - 1 + r, gc = wq0 - 1 + c;
        uint4 v = make_uint4(0u, 0u, 0u, 0u);
        if (gr >= 0 && gr < 32 && gc >= 0 && gc < 32)
            v = *(const uint4*)(zbfT + ((long)n * 1024 + gr * 32 + gc) * 256 + unit * 8);
        *(uint4*)(zbf + px * 264 + unit * 8) = v;
    }
    for (int idx = tid; idx < 576; idx += 256)
        mlds[idx] = maskb[((long)n * 1024 + hq * 32 + wq0) * 36 + idx];
    if (tid < 32)
        lw0s[tid] = lw0g[(long)n * 4096 + (h << 6) + w0 + tid];
    __syncthreads();

    const int w = tid & 31;
    const int chunk = tid >> 5;
    const float* i1 = i1g + (long)n * 256 * 4096 + (h << 6) + w0 + w;
    {
        const float lw = lw0s[w], lw1 = 1.f - lw;
        const int wp = w0 + w;
        const int wqm = (wp >> 1) - wq0;
        const int q = ((h & 1) << 1) | (wp & 1);
        float m9[9];
#pragma unroll
        for (int k = 0; k < 9; ++k) m9[k] = mlds[wqm * 36 + k * 4 + q];
        for (int ci = chunk * 32; ci < chunk * 32 + 32; ci += 8) {
            float uu[8];
            {
                float4 ba = *(const float4*)(bnp + 768 + ci);
                float4 bb = *(const float4*)(bnp + 768 + ci + 4);
                uu[0] = ba.x; uu[1] = ba.y; uu[2] = ba.z; uu[3] = ba.w;
                uu[4] = bb.x; uu[5] = bb.y; uu[6] = bb.z; uu[7] = bb.w;
            }
#pragma unroll
            for (int k = 0; k < 9; ++k) {
                int dh = k / 3 - 1, dw = k - (k / 3) * 3 - 1;
                uint4 vz = *(const uint4*)(zbf + ((1 + dh) * 18 + wqm + 1 + dw) * 264 + ci);
                float mk = m9[k];
                uu[0] += mk * bf2f((u16)(vz.x & 0xffff));
                uu[1] += mk * bf2f((u16)(vz.x >> 16));
                uu[2] += mk * bf2f((u16)(vz.y & 0xffff));
                uu[3] += mk * bf2f((u16)(vz.y >> 16));
                uu[4] += mk * bf2f((u16)(vz.z & 0xffff));
                uu[5] += mk * bf2f((u16)(vz.z >> 16));
                uu[6] += mk * bf2f((u16)(vz.w & 0xffff));
                uu[7] += mk * bf2f((u16)(vz.w >> 16));
            }
            unsigned o0 = (unsigned)f2bf(i1[(long)ci * 4096] * lw + uu[0] * lw1)
                        | ((unsigned)f2bf(i1[(long)(ci + 1) * 4096] * lw + uu[1] * lw1) << 16);
            unsigned o1 = (unsigned)f2bf(i1[(long)(ci + 2) * 4096] * lw + uu[2] * lw1)
                        | ((unsigned)f2bf(i1[(long)(ci + 3) * 4096] * lw + uu[3] * lw1) << 16);
            unsigned o2 = (unsigned)f2bf(i1[(long)(ci + 4) * 4096] * lw + uu[4] * lw1)
                        | ((unsigned)f2bf(i1[(long)(ci + 5) * 4096] * lw + uu[5] * lw1) << 16);
            unsigned o3 = (unsigned)f2bf(i1[(long)(ci + 6) * 4096] * lw + uu[6] * lw1)
                        | ((unsigned)f2bf(i1[(long)(ci + 7) * 4096] * lw + uu[7] * lw1) << 16);
            *(uint4*)(lds2 + w * 264 + ci) = make_uint4(o0, o1, o2, o3);
        }
    }
    __syncthreads();
    {
        const int px = tid >> 3, qd = tid & 7;
        const int pg = (h << 6) + w0 + px;
        long prow = (long)((pg >> 6) + 1) * 66 + (pg & 63) + 1;
        u16* drow = dst + (long)n * 4356 * 256 + prow * 256;
        const u16* lrow = lds2 + px * 264;
#pragma unroll
        for (int j = 0; j < 16; ++j) {
            int off = j * 16 + qd * 2;
            *(unsigned*)(drow + off) = *(const unsigned*)(lrow + off);
        }
    }
}

// ---------------- K7: m97 GEMM — post-barrier 2-deep staging, counted vmcnt ----------------
template<int KCC, int NT, bool PADDED>
__global__ __launch_bounds__(256, 2) void gemm_m97_kernel(
    const u16* __restrict__ A,      // [NT][256][KCC] bf16
    const u16* __restrict__ B,      // per image [rows][KCC] bf16
    const float* __restrict__ scale, const float* __restrict__ shift,
    float* __restrict__ C, long strideB, long strideC, int silu)
{
    constexpr int RROWS = PADDED ? 264 : 128;
    constexpr int BUNITS = RROWS * 4;
    constexpr int NKX = KCC / 32;
    constexpr int S = NKX * NT;
    __shared__ __align__(16) u16 lsA[3][128 * 32];
    __shared__ __align__(16) u16 lsB[2][RROWS * 32];
    const int n = blockIdx.z;
    const u16* Bn = B + (long)n * strideB;
    float* Cn = C + (long)n * strideC;
    const int tid = threadIdx.x;
    const int lane = tid & 63;
    const int wid = tid >> 6;
    const int mw = wid >> 1, nw = wid & 1;
    const int lr = lane & 15, lk = lane >> 4;
    const int rowBase = blockIdx.y * 128;
    const int colBase = blockIdx.x * 128;
    const int g0 = PADDED ? (colBase >> 6) * 66 : colBase;

    // prologue: B first, then A(0), A(1)  (VMCNT(2) at phase 0 leaves A(1))
    STAGE_B(lsB[0], 0);
    STAGE_A(lsA[0], 0, 0);
    STAGE_A(lsA[1], (NT > 1 ? 1 : 0), (NT > 1 ? 0 : 1));

    const int aswz = (lk ^ ((lr >> 1) & 3)) << 3;
    int aoff[4];
#pragma unroll
    for (int mf = 0; mf < 4; ++mf)
        aoff[mf] = (mw * 64 + mf * 16 + lr) * 32 + aswz;

    f32x4 acc[4][4] = {};
    for (int kx = 0; kx < NKX; ++kx) {
        const u16* lb = lsB[kx & 1];
#pragma unroll
        for (int t = 0; t < NT; ++t) {
            const int s = kx * NT + t;
            if (s == S - 1) { VMCNT(0); } else { VMCNT(2); }
            __builtin_amdgcn_s_barrier();
            asm volatile("" ::: "memory");
            // post-barrier issues (WAR-safe: no wave pre-barrier now)
            if (s + 2 < S) {
                const int s2 = s + 2;
                const int kx2 = s2 / NT;
                const int t2 = s2 - kx2 * NT;
                STAGE_A(lsA[s2 % 3], t2, kx2);
            }
            if (t == 0 && kx + 1 < NKX) STAGE_B(lsB[(kx + 1) & 1], kx + 1);

            const u16* la = lsA[s % 3];
            bf16x8 af[4], bfr[4];
#pragma unroll
            for (int mf = 0; mf < 4; ++mf)
                af[mf] = *(const bf16x8*)(la + aoff[mf]);
            int rb;
            if (PADDED) {
                int dh = t / 3 - 1, dw = t - (t / 3) * 3 - 1;
                rb = (nw + dh + 1) * 66 + dw + 1 + lr;
            } else {
                rb = nw * 64 + lr;
            }
            const int bswz = (lk ^ ((rb >> 1) & 3)) << 3;
#pragma unroll
            for (int nf = 0; nf < 4; ++nf)
                bfr[nf] = *(const bf16x8*)(lb + (rb + nf * 16) * 32 + bswz);
#pragma unroll
            for (int mf = 0; mf < 4; ++mf)
#pragma unroll
                for (int nf = 0; nf < 4; ++nf)
                    acc[mf][nf] = __builtin_amdgcn_mfma_f32_16x16x32_bf16(
                        af[mf], bfr[nf], acc[mf][nf], 0, 0, 0);
        }
    }

#pragma unroll
    for (int mf = 0; mf < 4; ++mf) {
#pragma unroll
        for (int reg = 0; reg < 4; ++reg) {
            int co = rowBase + mw * 64 + mf * 16 + lk * 4 + reg;
            float sc = scale[co], sh = shift[co];
#pragma unroll
            for (int nf = 0; nf < 4; ++nf) {
                int col = colBase + nw * 64 + nf * 16 + lr;
                float y = acc[mf][nf][reg] * sc + sh;
                if (silu) y = y / (1.f + expf(-y));
                Cn[(long)co * 4096 + col] = y;
            }
        }
    }
}

// ---------------- prep kernels ----------------
__global__ __launch_bounds__(256) void prep_w_kernel(
    const float* __restrict__ w_conv, const float* __restrict__ w_up,
    const float* __restrict__ w_enc, const float* __restrict__ w_down,
    u16* __restrict__ wT, u16* __restrict__ wupT, u16* __restrict__ wencT,
    u16* __restrict__ wdT)
{
    int gid = blockIdx.x * 256 + threadIdx.x;
    if (gid < 589824) {             // wT[t][co][ci] = w_conv[co][ci][t]
        int t = gid >> 16;
        int co = (gid >> 8) & 255;
        int ci = gid & 255;
        wT[gid] = f2bf(w_conv[(co * 256 + ci) * 9 + t]);
    }
    if (gid < 131072) wupT[gid] = f2bf(w_up[gid]);
    if (gid < 73728) {              // wencT[t][co<64][ci] (zeros co>=36)
        int t = gid >> 13;
        int co = (gid >> 7) & 63;
        int ci = gid & 127;
        wencT[gid] = (co < 36) ? f2bf(w_enc[(co * 128 + ci) * 9 + t]) : (u16)0;
    }
    if (gid < 65536) wdT[gid] = f2bf(w_down[gid]);
}

__global__ void prep_bn_kernel(const float* __restrict__ bn_conv,
                               const float* __restrict__ b_up,
                               const float* __restrict__ w_l2,
                               float* __restrict__ bnp, float* __restrict__ wl2T)
{
    int i = threadIdx.x;            // 256
    float g = bn_conv[i], b = bn_conv[256 + i], m = bn_conv[512 + i], v = bn_conv[768 + i];
    float sc = g * rsqrtf(v + EPS);
    bnp[i] = sc;
    bnp[256 + i] = b - m * sc;
    bnp[768 + i] = b_up[i];
    if (i < 8) {                    // c2[j] = w_l2[j] . b_up
        float s = 0.f;
        for (int co = 0; co < 256; ++co) s += w_l2[i * 256 + co] * b_up[co];
        bnp[512 + i] = s;
    }
#pragma unroll
    for (int j = 0; j < 8; ++j)     // wl2T[co][j]
        wl2T[i * 8 + j] = w_l2[j * 256 + i];
}

extern "C" void kernel_launch(void* const* d_in, const int* in_sizes, int n_in,
                              void* d_out, int out_size, void* d_ws, size_t ws_size,
                              hipStream_t stream)
{
    const float* input1 = (const float*)d_in[0];
    const float* input2 = (const float*)d_in[1];
    const float* w_down = (const float*)d_in[2];
    const float* b_down = (const float*)d_in[3];
    const float* w_enc  = (const float*)d_in[4];
    const float* b_enc  = (const float*)d_in[5];
    const float* w_up   = (const float*)d_in[6];
    const float* b_up   = (const float*)d_in[7];
    const float* w_l1   = (const float*)d_in[8];
    const float* bn_l1  = (const float*)d_in[9];
    const float* w_l2   = (const float*)d_in[10];
    const float* bn_l2  = (const float*)d_in[11];
    const float* w_wl   = (const float*)d_in[12];
    const float* b_wl   = (const float*)d_in[13];
    const float* w_conv = (const float*)d_in[14];
    const float* bn_conv= (const float*)d_in[15];
    float* out = (float*)d_out;

    // workspace layout (float units). ~38 MB total.
    float* ws     = (float*)d_ws;
    float* ktTf   = ws;                      //   591,872 f : ktT bf16 [n][1156][128]
    float* wencTf = ktTf + 591872;           //    36,864 f
    float* kt2    = wencTf + 36864;          //   294,912 f
    float* maskb  = kt2 + 294912;            //   294,912 f
    float* in2Tf  = maskb + 294912;          // 2,097,152 f : in2T bf16 [n][1024][512]
    float* zbfTf  = in2Tf + 2097152;         // 1,048,576 f : zbfT bf16 [n][1024][256]
    float* zwT    = zbfTf + 1048576;         //    65,536 f : [n][1024][8] fp32
    float* lw0g   = zwT + 65536;             //    32,768 f : [n][4096]
    float* ftbf   = lw0g + 32768;            // 4,460,544 f : fusedT bf16 [n][4356][256]
    float* wTf    = ftbf + 4460544;          //   294,912 f
    float* wupTf  = wTf + 294912;            //    65,536 f
    float* wdTf   = wupTf + 65536;           //    32,768 f
    float* wl2T   = wdTf + 32768;            //     2,048 f
    float* bnp    = wl2T + 2048;             //     1,024 f
    u16* ktT      = (u16*)ktTf;
    u16* wencT    = (u16*)wencTf;
    u16* in2T     = (u16*)in2Tf;
    u16* zbfT     = (u16*)zbfTf;
    u16* ftb      = (u16*)ftbf;
    u16* wT       = (u16*)wTf;
    u16* wupT     = (u16*)wupTf;
    u16* wdT      = (u16*)wdTf;

    // prep (independent)
    prep_w_kernel<<<dim3(2304), 256, 0, stream>>>(w_conv, w_up, w_enc, w_down,
                                                  wT, wupT, wencT, wdT);
    prep_bn_kernel<<<dim3(1), 256, 0, stream>>>(bn_conv, b_up, w_l2, bnp, wl2T);
    border_zero_kernel<<<dim3(260), 256, 0, stream>>>(ftb);
    hipMemsetAsync(ktT, 0, 8L * 1156 * 128 * 2, stream);

    // in2T first (feeds down_mfma and zgemm)
    in2t_kernel<<<dim3(32, 8), 256, 0, stream>>>(input2, in2T);

    // mask pipeline
    down_mfma_kernel<<<dim3(8, 1, 8), 256, 0, stream>>>(wdT, in2T, b_down, ktT);
    enc_mfma_kernel<<<dim3(64, 8), 64, 0, stream>>>(wencT, ktT, b_enc, kt2);
    mask_softmax_kernel<<<dim3(128), 256, 0, stream>>>(kt2, maskb);

    // z pipeline
    zgemm_kernel<<<dim3(8, 2, 8), 256, 0, stream>>>(wupT, in2T, zbfT);
    zw_kernel<<<dim3(2048), 256, 0, stream>>>(zbfT, wl2T, zwT);

    // level weights -> lw0 (reads i1 once)
    fuse_weights_kernel<<<dim3(512), 256, 0, stream>>>(
        input1, zwT, maskb, bnp, w_l1, bn_l1, bn_l2, w_wl, b_wl, lw0g);

    // CARAFE + blend -> fusedT
    carafe_blend_kernel<<<dim3(128, 8), 256, 0, stream>>>(
        input1, zbfT, maskb, lw0g, bnp, ftb);

    // K7: final conv + BN + SiLU
    gemm_m97_kernel<256, 9, true><<<dim3(32, 2, 8), 256, 0, stream>>>(
        wT, ftb, bnp, bnp + 256, out, 4356L * 256, 256L * 4096, 1);
}